// Round 7
// baseline (1529.740 us; speedup 1.0000x reference)
//
#include <hip/hip_runtime.h>
#include <math.h>

typedef _Float16 f16;
typedef _Float16 f16x8 __attribute__((ext_vector_type(8)));
typedef _Float16 f16x2 __attribute__((ext_vector_type(2)));
typedef float f32x4 __attribute__((ext_vector_type(4)));

#define TT 1024
#define HH 128
#define SROWH 144    // halves per A_s row: 72 dwords -> 8-dword bank shift/row
#define XROW 648     // halves per xg_lds stream row (16 li-blocks of 40, padded)
#define NEV 24

__device__ __forceinline__ float sigm(float x){ return 1.f/(1.f + __expf(-x)); }
__device__ __forceinline__ float tanh_f(float x){
    float e = __expf(2.f*x);
    return 1.f - 2.f/(e + 1.f);
}

#define MF(a,b,c) __builtin_amdgcn_mfma_f32_16x16x32_f16((a),(b),(c),0,0,0)

// ---------------- prep ----------------
// Whh_p[j][k'] : k' = sigma(u) permutation (u = w*32 + h4*16 + li  <->  k' = li*8 + w*2 + h4)
// Wih_p rows j = nt*16+li hold W_ih row (g*128+u) with g=(j>>4)&3, u=(j>>6)*16+(j&15)  [xg_gemm tiling]
// bsum_o / Wg_o in xg p-order: p = (u&15)*32 + (u>>4)*4 + g
__global__ void pack_kernel(const float* __restrict__ W_ih, const float* __restrict__ W_hh,
                            const float* __restrict__ b_ih, const float* __restrict__ b_hh,
                            const float* __restrict__ Wi, const float* __restrict__ Wc, const float* __restrict__ Wo,
                            f16* __restrict__ Whh_p, f16* __restrict__ Wih_p,
                            float* __restrict__ Wg_o, float* __restrict__ bsum_o, float* __restrict__ WT)
{
    int idx = blockIdx.x*256 + threadIdx.x;
    if (idx < 512*128){
        {   // Whh_p with k-permutation
            int j = idx >> 7, kp = idx & 127;
            int lp = kp >> 3, r = kp & 7, wq = r >> 1, h4 = r & 1;
            int u = wq*32 + h4*16 + lp;
            Whh_p[idx] = (f16)W_hh[j*128 + u];
        }
        {   // Wih_p for xg_gemm
            int j = idx >> 7, k = idx & 127;
            int g = (j >> 4) & 3;
            int u = ((j >> 6) << 4) | (j & 15);
            Wih_p[idx] = (f16)W_ih[(g*128 + u)*130 + k];
        }
    }
    if (idx < 1024){
        int p = idx >> 1, c = idx & 1;
        int lp = p >> 5, rem = p & 31, uh = rem >> 2, g = rem & 3;
        int u = uh*16 + lp;
        Wg_o[idx] = W_ih[(g*128 + u)*130 + 128 + c];
    }
    if (idx < 512){
        int p = idx;
        int lp = p >> 5, rem = p & 31, uh = rem >> 2, g = rem & 3;
        int u = uh*16 + lp;
        bsum_o[p] = b_ih[g*128 + u] + b_hh[g*128 + u];
    }
    if (idx < 3*128*128){
        int w = idx >> 14, rem = idx & 16383, k = rem >> 7, u = rem & 127;
        const float* W = (w==0) ? Wi : (w==1) ? Wc : Wo;
        WT[idx] = W[u*128 + k];   // WT[w][k][u] = W[u][k]
    }
}

// ---------------- precompute xgT[word][p] = (E0[word] . W_ih[:, :128]^T), f16, p-order ----------------
__global__ void xg_gemm(const float* __restrict__ E, const f16* __restrict__ Wih_p,
                        f16* __restrict__ xgT, int NW)
{
    const int w = threadIdx.x >> 6, lane = threadIdx.x & 63;
    const int li = lane & 15, q = lane >> 4;
    const int word = blockIdx.x*128 + w*16 + li;

    f16x8 a[4];
    const bool valid = (word > 0) && (word < NW);
    #pragma unroll
    for (int ks = 0; ks < 4; ++ks){
        f32x4 v0 = {0.f,0.f,0.f,0.f}, v1 = v0;
        if (valid){
            const f32x4* Er = (const f32x4*)(E + (size_t)word*HH);
            v0 = Er[ks*8 + q*2];
            v1 = Er[ks*8 + q*2 + 1];
        }
        f16x8 t;
        t[0]=(f16)v0[0]; t[1]=(f16)v0[1]; t[2]=(f16)v0[2]; t[3]=(f16)v0[3];
        t[4]=(f16)v1[0]; t[5]=(f16)v1[1]; t[6]=(f16)v1[2]; t[7]=(f16)v1[3];
        a[ks] = t;
    }
    const int wbase = blockIdx.x*128 + w*16 + q*4;
    #pragma unroll
    for (int grp = 0; grp < 4; ++grp){
        f32x4 acc_t[8];
        #pragma unroll
        for (int j8 = 0; j8 < 8; ++j8){
            const int nt = grp*8 + j8;
            f32x4 acc = {0.f,0.f,0.f,0.f};
            #pragma unroll
            for (int ks = 0; ks < 4; ++ks){
                f16x8 b = *reinterpret_cast<const f16x8*>(Wih_p + (size_t)(nt*16 + li)*128 + ks*32 + q*8);
                acc = MF(a[ks], b, acc);
            }
            acc_t[j8] = acc;
        }
        #pragma unroll
        for (int r = 0; r < 4; ++r){
            int wr = wbase + r;
            if (wr < NW){
                f16x8 v;
                #pragma unroll
                for (int j8 = 0; j8 < 8; ++j8) v[j8] = (f16)acc_t[j8][r];
                *reinterpret_cast<f16x8*>(xgT + (size_t)wr*512 + li*32 + grp*8) = v;
            }
        }
    }
}

// ---------------- prep: length sort + per-stream sorted event lists ----------------
__device__ __forceinline__ void add_ev(int* et, int* es, int& n, int t, int slot, int len){
    if (t < 0 || t >= len) return;
    int p = n++;
    while (p > 0 && et[p-1] > t){ et[p] = et[p-1]; es[p] = es[p-1]; --p; }
    et[p] = t; es[p] = slot;
}

__global__ void sched_kernel(const int* __restrict__ len_t, const int* __restrict__ len_a, const int* __restrict__ len_f,
                             const int* __restrict__ sub_ta, const int* __restrict__ sub_tf,
                             const int* __restrict__ sub_a, const int* __restrict__ sub_f,
                             int* __restrict__ order, int* __restrict__ slen,
                             int* __restrict__ ev_t, int* __restrict__ ev_slot, int* __restrict__ nev)
{
    __shared__ int L[768];
    int s = threadIdx.x;              // 0..767, stream id = e*256 + b
    int e = s >> 8, b = s & 255;
    int len = (e==0) ? len_t[b] : (e==1) ? len_a[b] : len_f[b];
    L[s] = len;
    __syncthreads();
    int rank = 0;
    for (int i = 0; i < 768; ++i){
        int li = L[i];
        rank += (li > len) || (li == len && i < s);
    }
    order[rank] = s;                  // descending by length, bijective
    slen[s] = len;

    int et[NEV], es[NEV]; int n = 0;
    if (e == 0){
        for (int r = 0; r < 10; ++r){
            add_ev(et, es, n, sub_ta[b*10+r]-1, b*10+r,        len);
            add_ev(et, es, n, sub_tf[b*10+r]-1, 2560 + b*10+r, len);
        }
    } else if (e == 1){
        for (int r = 0; r < 10; ++r) add_ev(et, es, n, sub_a[b*10+r]-1, 5120 + b*10+r, len);
    } else {
        for (int r = 0; r < 10; ++r) add_ev(et, es, n, sub_f[b*10+r]-1, 7680 + b*10+r, len);
    }
    add_ev(et, es, n, len-1, 10240 + s, len);   // final hidden state
    nev[s] = n;
    for (int i = 0; i < n; ++i){ ev_t[s*NEV+i] = et[i]; ev_slot[s*NEV+i] = es[i]; }
}

// ---------------- main LSTM: 7 waves = 4 fat compute (32 MFMA) + 3 staging (full gate-base fold) ----------------
__launch_bounds__(448, 1)
__global__ void lstm_kernel(const float* __restrict__ gps0, const float* __restrict__ gps1, const float* __restrict__ gps2,
                            const int* __restrict__ grid0, const int* __restrict__ grid1, const int* __restrict__ grid2,
                            const f16* __restrict__ xgT, const f16* __restrict__ Whh_p,
                            const float* __restrict__ Wg_o, const float* __restrict__ bsum_o,
                            const int* __restrict__ order, const int* __restrict__ slen,
                            const int* __restrict__ ev_t, const int* __restrict__ ev_slot, const int* __restrict__ nev,
                            float* __restrict__ stash)
{
    __shared__ f16 A_s[2][4][SROWH];      // h (k'-permuted) per stream row 0..2, row 3 zero; double-buffered
    __shared__ f16 xg_lds[2][3][XROW];    // folded gate base (xg+bias+gps), p-order w/ 40-stride; double-buffered
    __shared__ int ev_t_s[3][NEV];
    __shared__ int ev_sl_s[3][NEV];

    const int tid  = threadIdx.x;
    const int lane = tid & 63;
    const int wv   = tid >> 6;          // 0..3 compute, 4..6 staging
    const int q    = lane >> 4;
    const int li   = lane & 15;
    const int qc   = (q < 3) ? q : 2;
    const int u0   = (wv << 5) + li;    // compute: first unit of this lane
    const int bi   = blockIdx.x;

    const int s0 = order[bi], s1 = order[bi+256], s2 = order[bi+512];
    const int l0 = slen[s0], l1 = slen[s1], l2 = slen[s2];
    int maxlen = l0 > l1 ? l0 : l1; if (l2 > maxlen) maxlen = l2;

    // ---- init LDS ----
    for (int i = tid; i < 2*4*SROWH; i += 448) (&A_s[0][0][0])[i] = (f16)0.f;
    if (tid < 72){
        int m = tid / NEV, i = tid % NEV;
        int sm = (m==0) ? s0 : (m==1) ? s1 : s2;
        ev_t_s[m][i]  = ev_t[sm*NEV + i];
        ev_sl_s[m][i] = ev_slot[sm*NEV + i];
    }

    // ---- compute-wave persistent state ----
    f16x8 wfr[2][4][4];
    float cr[2] = {0.f, 0.f}, hr[2] = {0.f, 0.f};
    int len_q = 0, nev_q = 0, evp = 0, next_t = 1<<30;

    // ---- staging persistent state ----
    f16x8 xgb[4] = {};
    float gpx[4] = {}, gpy[4] = {};
    int   idq[4] = {};
    float bs8[8], wgx[8], wgy[8];
    const float* gps_p = nullptr;
    const int*   grid_p = nullptr;

    if (wv < 4){
        #pragma unroll
        for (int nt = 0; nt < 2; ++nt)
            #pragma unroll
            for (int g = 0; g < 4; ++g){
                const size_t row = (size_t)(g*128 + (wv<<5) + (nt<<4) + li) * 128;
                #pragma unroll
                for (int ks = 0; ks < 4; ++ks)
                    wfr[nt][g][ks] = *reinterpret_cast<const f16x8*>(Whh_p + row + ks*32 + (q<<3));
            }
        if (q < 3){
            int sq = (q==0)?s0:(q==1)?s1:s2;
            len_q = (q==0)?l0:(q==1)?l1:l2;
            nev_q = nev[sq];
        }
        #pragma unroll
        for (int k = 0; k < 8; ++k){ bs8[k]=0.f; wgx[k]=0.f; wgy[k]=0.f; }
    } else {
        const int sm = wv - 4;
        const int ss = (sm==0)?s0:(sm==1)?s1:s2;
        gps_p  = ((ss>>8)==0 ? gps0 : (ss>>8)==1 ? gps1 : gps2) + (size_t)(ss&255)*(TT*2);
        grid_p = ((ss>>8)==0 ? grid0 : (ss>>8)==1 ? grid1 : grid2) + (size_t)(ss&255)*TT;
        {
            const float* bp = bsum_o + (lane << 3);
            f32x4 b0 = *reinterpret_cast<const f32x4*>(bp);
            f32x4 b1 = *reinterpret_cast<const f32x4*>(bp + 4);
            bs8[0]=b0[0]; bs8[1]=b0[1]; bs8[2]=b0[2]; bs8[3]=b0[3];
            bs8[4]=b1[0]; bs8[5]=b1[1]; bs8[6]=b1[2]; bs8[7]=b1[3];
            const float* wp = Wg_o + (lane << 4);
            f32x4 w0 = *reinterpret_cast<const f32x4*>(wp);
            f32x4 w1 = *reinterpret_cast<const f32x4*>(wp + 4);
            f32x4 w2 = *reinterpret_cast<const f32x4*>(wp + 8);
            f32x4 w3 = *reinterpret_cast<const f32x4*>(wp + 12);
            wgx[0]=w0[0]; wgy[0]=w0[1]; wgx[1]=w0[2]; wgy[1]=w0[3];
            wgx[2]=w1[0]; wgy[2]=w1[1]; wgx[3]=w1[2]; wgy[3]=w1[3];
            wgx[4]=w2[0]; wgy[4]=w2[1]; wgx[5]=w2[2]; wgy[5]=w2[3];
            wgx[6]=w3[0]; wgy[6]=w3[1]; wgx[7]=w3[2]; wgy[7]=w3[3];
        }
    }

    __syncthreads();   // LDS zero-init + ev lists visible

    // ---- prologue ----
    if (wv >= 4){
        const int sm = wv - 4;
        // t=0 fold & deposit
        int i0 = grid_p[0];
        f16x8 x0 = *reinterpret_cast<const f16x8*>(xgT + (size_t)i0*512 + (lane<<3));
        const float2 g00 = *reinterpret_cast<const float2*>(gps_p);
        f16x8 o0;
        #pragma unroll
        for (int s2 = 0; s2 < 8; ++s2){
            float v = (float)x0[s2] + bs8[s2] + g00.x*wgx[s2] + g00.y*wgy[s2];
            o0[s2] = (f16)v;
        }
        *reinterpret_cast<f16x8*>(&xg_lds[0][sm][(lane>>2)*40 + ((lane&3)<<3)]) = o0;
        // prime 4-deep pipelines (rows t=1..4, indices t&3)
        int i1 = grid_p[1], i2 = grid_p[2], i3 = grid_p[3], i4 = grid_p[4];
        xgb[1] = *reinterpret_cast<const f16x8*>(xgT + (size_t)i1*512 + (lane<<3));
        xgb[2] = *reinterpret_cast<const f16x8*>(xgT + (size_t)i2*512 + (lane<<3));
        xgb[3] = *reinterpret_cast<const f16x8*>(xgT + (size_t)i3*512 + (lane<<3));
        xgb[0] = *reinterpret_cast<const f16x8*>(xgT + (size_t)i4*512 + (lane<<3));
        float2 g1 = *reinterpret_cast<const float2*>(gps_p + 2);
        float2 g2 = *reinterpret_cast<const float2*>(gps_p + 4);
        float2 g3 = *reinterpret_cast<const float2*>(gps_p + 6);
        float2 g4 = *reinterpret_cast<const float2*>(gps_p + 8);
        gpx[1]=g1.x; gpy[1]=g1.y; gpx[2]=g2.x; gpy[2]=g2.y;
        gpx[3]=g3.x; gpy[3]=g3.y; gpx[0]=g4.x; gpy[0]=g4.y;
        idq[1] = grid_p[5]; idq[2] = grid_p[6]; idq[3] = grid_p[7]; idq[0] = grid_p[8];
    } else if (q < 3){
        if (nev_q > 0) next_t = ev_t_s[q][0];
    }
    __syncthreads();

#define STEP(T, P, P1, F1)                                                                  \
{                                                                                           \
    if (wv < 4){                                                                            \
        f16x8 av[4];                                                                        \
        const f16* Arow = &A_s[P][li >> 2][q << 3];                                         \
        _Pragma("unroll")                                                                   \
        for (int ks = 0; ks < 4; ++ks)                                                      \
            av[ks] = *reinterpret_cast<const f16x8*>(Arow + ks*32);                         \
        f16x8 xgv = *reinterpret_cast<const f16x8*>(&xg_lds[P][qc][li*40 + (wv<<3)]);       \
        f32x4 ac[2][4];                                                                     \
        _Pragma("unroll")                                                                   \
        for (int nt = 0; nt < 2; ++nt)                                                      \
            _Pragma("unroll")                                                               \
            for (int g = 0; g < 4; ++g){                                                    \
                float v = (float)xgv[nt*4 + g];                                             \
                ac[nt][g][0]=v; ac[nt][g][1]=v; ac[nt][g][2]=v; ac[nt][g][3]=v;             \
            }                                                                               \
        __builtin_amdgcn_s_setprio(1);                                                      \
        _Pragma("unroll")                                                                   \
        for (int ks = 0; ks < 4; ++ks){                                                     \
            ac[0][0] = MF(av[ks], wfr[0][0][ks], ac[0][0]);                                 \
            ac[0][1] = MF(av[ks], wfr[0][1][ks], ac[0][1]);                                 \
            ac[0][2] = MF(av[ks], wfr[0][2][ks], ac[0][2]);                                 \
            ac[0][3] = MF(av[ks], wfr[0][3][ks], ac[0][3]);                                 \
            ac[1][0] = MF(av[ks], wfr[1][0][ks], ac[1][0]);                                 \
            ac[1][1] = MF(av[ks], wfr[1][1][ks], ac[1][1]);                                 \
            ac[1][2] = MF(av[ks], wfr[1][2][ks], ac[1][2]);                                 \
            ac[1][3] = MF(av[ks], wfr[1][3][ks], ac[1][3]);                                 \
        }                                                                                   \
        __builtin_amdgcn_s_setprio(0);                                                      \
        if (q < 3){                                                                         \
            if ((T) < len_q){                                                               \
                _Pragma("unroll")                                                           \
                for (int nt = 0; nt < 2; ++nt){                                             \
                    float si = sigm(ac[nt][0][0]);                                          \
                    float sf = sigm(ac[nt][1][0]);                                          \
                    float tg = tanh_f(ac[nt][2][0]);                                        \
                    float so = sigm(ac[nt][3][0]);                                          \
                    cr[nt] = sf * cr[nt] + si * tg;                                         \
                    hr[nt] = so * tanh_f(cr[nt]);                                           \
                }                                                                           \
                while ((T) == next_t){                                                      \
                    const int sl = ev_sl_s[q][evp];                                         \
                    stash[(size_t)sl*HH + u0]      = hr[0];                                 \
                    stash[(size_t)sl*HH + u0 + 16] = hr[1];                                 \
                    ++evp;                                                                  \
                    next_t = (evp < nev_q) ? ev_t_s[q][evp] : (1<<30);                      \
                }                                                                           \
            }                                                                               \
            f16x2 hp; hp[0] = (f16)hr[0]; hp[1] = (f16)hr[1];                               \
            *reinterpret_cast<f16x2*>(&A_s[P1][q][(li<<3) + (wv<<1)]) = hp;                 \
        }                                                                                   \
    } else {                                                                                \
        const int sm = wv - 4;                                                              \
        f16x8 xv = xgb[F1];                                                                 \
        const float gx = gpx[F1], gy = gpy[F1];                                             \
        f16x8 outv;                                                                         \
        _Pragma("unroll")                                                                   \
        for (int s2 = 0; s2 < 8; ++s2){                                                     \
            float v = (float)xv[s2] + bs8[s2] + gx*wgx[s2] + gy*wgy[s2];                    \
            outv[s2] = (f16)v;                                                              \
        }                                                                                   \
        *reinterpret_cast<f16x8*>(&xg_lds[P1][sm][(lane>>2)*40 + ((lane&3)<<3)]) = outv;    \
        xgb[F1] = *reinterpret_cast<const f16x8*>(xgT + (size_t)idq[F1]*512 + (lane<<3));   \
        int t5 = (T)+5; if (t5 > TT-1) t5 = TT-1;                                           \
        const float2 gg = *reinterpret_cast<const float2*>(gps_p + (size_t)t5*2);           \
        gpx[F1] = gg.x; gpy[F1] = gg.y;                                                     \
        int t9 = (T)+9; if (t9 > TT-1) t9 = TT-1;                                           \
        idq[F1] = grid_p[t9];                                                               \
    }                                                                                       \
    asm volatile("s_waitcnt lgkmcnt(0)" ::: "memory");                                      \
    __builtin_amdgcn_s_barrier();                                                           \
    asm volatile("" ::: "memory");                                                          \
}

    int t = 0;
    for (; t + 3 < maxlen; t += 4){
        STEP(t,   0, 1, 1);
        STEP(t+1, 1, 0, 2);
        STEP(t+2, 0, 1, 3);
        STEP(t+3, 1, 0, 0);
    }
    if (t < maxlen)     STEP(t,   0, 1, 1);
    if (t+1 < maxlen)   STEP(t+1, 1, 0, 2);
    if (t+2 < maxlen)   STEP(t+2, 0, 1, 3);
#undef STEP
}

// ---------------- fsim applied in-place on the stash (fp32, LDS-staged transposed weights) ----------------
__global__ void fsim_kernel(float* __restrict__ stash, const float* __restrict__ WT,
                            const float* __restrict__ bi, const float* __restrict__ bc, const float* __restrict__ bo,
                            const int* __restrict__ sub_ta, const int* __restrict__ sub_tf,
                            const int* __restrict__ sub_a, const int* __restrict__ sub_f,
                            const int* __restrict__ len_t, const int* __restrict__ len_a, const int* __restrict__ len_f)
{
    __shared__ float h_s[64][HH];
    __shared__ float w_s[3][32][HH];
    const int tid = threadIdx.x;
    const int base = blockIdx.x * 64;

    for (int i = tid; i < 64*HH; i += 256){
        int v = i >> 7, k = i & 127;
        int row = base + v;
        bool valid = true;
        if (row < 10240){
            int g = row / 2560, rr = row % 2560, b = rr / 10;
            int sub, len;
            if (g == 0){ sub = sub_ta[rr]; len = len_t[b]; }
            else if (g == 1){ sub = sub_tf[rr]; len = len_t[b]; }
            else if (g == 2){ sub = sub_a[rr]; len = len_a[b]; }
            else { sub = sub_f[rr]; len = len_f[b]; }
            valid = (sub - 1) < len;    // y is zero past length
        }
        h_s[v][k] = valid ? stash[(size_t)row * HH + k] : 0.f;
    }
    __syncthreads();

    const int uu = tid & 127;
    const int vb = (tid >> 7) << 5;
    float aI[32], aC[32], aO[32];
    #pragma unroll
    for (int v = 0; v < 32; ++v){ aI[v]=0.f; aC[v]=0.f; aO[v]=0.f; }

    for (int kc = 0; kc < 4; ++kc){
        for (int i = tid; i < 3*32*HH; i += 256){
            int w = i >> 12, rem = i & 4095, kk = rem >> 7, u2 = rem & 127;
            w_s[w][kk][u2] = WT[(size_t)w*16384 + (size_t)(kc*32 + kk)*HH + u2];
        }
        __syncthreads();
        for (int kk = 0; kk < 32; ++kk){
            float wi = w_s[0][kk][uu], wc = w_s[1][kk][uu], wo = w_s[2][kk][uu];
            #pragma unroll
            for (int v = 0; v < 32; ++v){
                float h = h_s[vb + v][kc*32 + kk];
                aI[v] = fmaf(h, wi, aI[v]);
                aC[v] = fmaf(h, wc, aC[v]);
                aO[v] = fmaf(h, wo, aO[v]);
            }
        }
        __syncthreads();
    }
    float BI = bi[uu], BC = bc[uu], BO = bo[uu];
    #pragma unroll
    for (int v = 0; v < 32; ++v){
        float C   = sigm(aI[v] + BI) * tanh_f(aC[v] + BC);
        float out = sigm(aO[v] + BO) * tanh_f(C) + h_s[vb + v][uu];
        stash[(size_t)(base + vb + v) * HH + uu] = out;
    }
}

// ---------------- distances: out = exp(-||u - v||) ----------------
__global__ void dist_kernel(const float* __restrict__ fs, float* __restrict__ out)
{
    int gid = blockIdx.x * 256 + threadIdx.x;
    int pair = gid >> 6, ln = gid & 63;
    if (pair >= 5632) return;
    int ia, ib;
    if (pair < 256){ ia = 10240 + pair; ib = 10240 + 256 + pair; }
    else if (pair < 512){ int j = pair - 256; ia = 10240 + j; ib = 10240 + 512 + j; }
    else if (pair < 3072){ int j = pair - 512; ia = j; ib = 5120 + j; }
    else { int j = pair - 3072; ia = 2560 + j; ib = 7680 + j; }
    float d = 0.f;
    #pragma unroll
    for (int k = 0; k < 2; ++k){
        int kk = ln + k*64;
        float df = fs[(size_t)ia*HH + kk] - fs[(size_t)ib*HH + kk];
        d = fmaf(df, df, d);
    }
    #pragma unroll
    for (int off = 32; off > 0; off >>= 1) d += __shfl_xor(d, off);
    if (ln == 0) out[pair] = __expf(-sqrtf(d));
}

extern "C" void kernel_launch(void* const* d_in, const int* in_sizes, int n_in,
                              void* d_out, int out_size, void* d_ws, size_t ws_size,
                              hipStream_t stream)
{
    (void)n_in; (void)out_size; (void)ws_size;
    const float* traj_gps = (const float*)d_in[0];
    const int*   traj_grid = (const int*)d_in[2];
    const int*   traj_len = (const int*)d_in[4];
    const int*   sub_ta = (const int*)d_in[5];
    const int*   sub_tf = (const int*)d_in[6];
    const float* anc_gps = (const float*)d_in[7];
    const int*   anc_grid = (const int*)d_in[9];
    const int*   anc_len = (const int*)d_in[11];
    const int*   sub_a = (const int*)d_in[12];
    const float* far_gps = (const float*)d_in[13];
    const int*   far_grid = (const int*)d_in[15];
    const int*   far_len = (const int*)d_in[17];
    const int*   sub_f = (const int*)d_in[18];
    const float* E    = (const float*)d_in[19];
    const float* W_ih = (const float*)d_in[20];
    const float* W_hh = (const float*)d_in[21];
    const float* b_ih = (const float*)d_in[22];
    const float* b_hh = (const float*)d_in[23];
    const float* Wi = (const float*)d_in[24];
    const float* bi = (const float*)d_in[25];
    const float* Wc = (const float*)d_in[26];
    const float* bc = (const float*)d_in[27];
    const float* Wo = (const float*)d_in[28];
    const float* bo = (const float*)d_in[29];

    const int NW_rt = in_sizes[19] / HH;   // 50000

    char* p = (char*)d_ws;
    f16* Whh_p    = (f16*)p;   p += (size_t)512*128*2;
    f16* Wih_p    = (f16*)p;   p += (size_t)512*128*2;
    float* Wg_o   = (float*)p; p += 1024*4;
    float* bsum_o = (float*)p; p += 512*4;
    float* WT     = (float*)p; p += (size_t)3*128*128*4;
    int* order    = (int*)p;   p += 768*4;
    int* slen     = (int*)p;   p += 768*4;
    int* ev_t     = (int*)p;   p += 768*NEV*4;
    int* ev_slot  = (int*)p;   p += 768*NEV*4;
    int* nev      = (int*)p;   p += 768*4;
    float* stash  = (float*)p; p += (size_t)11008*128*4;
    f16* xgT      = (f16*)p;   p += (size_t)NW_rt*512*2;

    pack_kernel<<<576, 256, 0, stream>>>(W_ih, W_hh, b_ih, b_hh, Wi, Wc, Wo,
                                         Whh_p, Wih_p, Wg_o, bsum_o, WT);
    xg_gemm<<<(NW_rt + 127)/128, 512, 0, stream>>>(E, Wih_p, xgT, NW_rt);
    sched_kernel<<<1, 768, 0, stream>>>(traj_len, anc_len, far_len, sub_ta, sub_tf, sub_a, sub_f,
                                        order, slen, ev_t, ev_slot, nev);
    lstm_kernel<<<256, 448, 0, stream>>>(traj_gps, anc_gps, far_gps, traj_grid, anc_grid, far_grid,
                                         xgT, Whh_p, Wg_o, bsum_o, order, slen, ev_t, ev_slot, nev, stash);
    fsim_kernel<<<172, 256, 0, stream>>>(stash, WT, bi, bc, bo, sub_ta, sub_tf, sub_a, sub_f,
                                         traj_len, anc_len, far_len);
    dist_kernel<<<1408, 256, 0, stream>>>(stash, (float*)d_out);
}

// Round 8
// 1184.441 us; speedup vs baseline: 1.2915x; 1.2915x over previous
//
#include <hip/hip_runtime.h>
#include <math.h>

typedef _Float16 f16;
typedef _Float16 f16x8 __attribute__((ext_vector_type(8)));
typedef _Float16 f16x4 __attribute__((ext_vector_type(4)));
typedef float f32x4 __attribute__((ext_vector_type(4)));

#define TT 1024
#define HH 128
#define SROWH 144    // halves per A_s row: 72 dwords -> 8-dword bank shift/row, 2-way max on frag reads
#define NEV 24

__device__ __forceinline__ float sigm(float x){ return 1.f/(1.f + __expf(-x)); }
__device__ __forceinline__ float tanh_f(float x){
    float e = __expf(2.f*x);
    return 1.f - 2.f/(e + 1.f);
}

#define MF(a,b,c) __builtin_amdgcn_mfma_f32_16x16x32_f16((a),(b),(c),0,0,0)

// ---------------- prep ----------------
// Whh_p: plain f16 copy of W_hh (rows j = g*128+u, k = 0..127)
// Wih_p: rows j = nt*16+li_w hold W_ih row (g*128+u) with p=li_w*32+nt, u=p>>2, g=p&3 (xg_gemm tiling,
//        so xgT[word][p] has p = u*4+g : the 4 gates of unit u are contiguous)
// bsum_o/Wg_o in the same p-order
__global__ void pack_kernel(const float* __restrict__ W_ih, const float* __restrict__ W_hh,
                            const float* __restrict__ b_ih, const float* __restrict__ b_hh,
                            const float* __restrict__ Wi, const float* __restrict__ Wc, const float* __restrict__ Wo,
                            f16* __restrict__ Whh_p, f16* __restrict__ Wih_p,
                            float* __restrict__ Wg_o, float* __restrict__ bsum_o, float* __restrict__ WT)
{
    int idx = blockIdx.x*256 + threadIdx.x;
    if (idx < 512*128){
        Whh_p[idx] = (f16)W_hh[idx];
        int j = idx >> 7, k = idx & 127;
        int p = ((j & 15) << 5) + (j >> 4);   // li_w*32 + nt
        int u = p >> 2, g = p & 3;
        Wih_p[idx] = (f16)W_ih[(g*128 + u)*130 + k];
    }
    if (idx < 1024){
        int p = idx >> 1, c = idx & 1;
        int u = p >> 2, g = p & 3;
        Wg_o[idx] = W_ih[(g*128 + u)*130 + 128 + c];   // [p][c]
    }
    if (idx < 512){
        int u = idx >> 2, g = idx & 3;
        bsum_o[idx] = b_ih[g*128 + u] + b_hh[g*128 + u];
    }
    if (idx < 3*128*128){
        int w = idx >> 14, rem = idx & 16383, k = rem >> 7, u = rem & 127;
        const float* W = (w==0) ? Wi : (w==1) ? Wc : Wo;
        WT[idx] = W[u*128 + k];   // WT[w][k][u] = W[u][k]
    }
}

// ---------------- precompute xgT[word][p] = (E0[word] . W_ih[:, :128]^T), f16, p-order ----------------
__global__ void xg_gemm(const float* __restrict__ E, const f16* __restrict__ Wih_p,
                        f16* __restrict__ xgT, int NW)
{
    const int w = threadIdx.x >> 6, lane = threadIdx.x & 63;
    const int li = lane & 15, q = lane >> 4;
    const int word = blockIdx.x*128 + w*16 + li;

    f16x8 a[4];
    const bool valid = (word > 0) && (word < NW);
    #pragma unroll
    for (int ks = 0; ks < 4; ++ks){
        f32x4 v0 = {0.f,0.f,0.f,0.f}, v1 = v0;
        if (valid){
            const f32x4* Er = (const f32x4*)(E + (size_t)word*HH);
            v0 = Er[ks*8 + q*2];
            v1 = Er[ks*8 + q*2 + 1];
        }
        f16x8 t;
        t[0]=(f16)v0[0]; t[1]=(f16)v0[1]; t[2]=(f16)v0[2]; t[3]=(f16)v0[3];
        t[4]=(f16)v1[0]; t[5]=(f16)v1[1]; t[6]=(f16)v1[2]; t[7]=(f16)v1[3];
        a[ks] = t;
    }
    const int wbase = blockIdx.x*128 + w*16 + q*4;
    #pragma unroll
    for (int grp = 0; grp < 4; ++grp){
        f32x4 acc_t[8];
        #pragma unroll
        for (int j8 = 0; j8 < 8; ++j8){
            const int nt = grp*8 + j8;
            f32x4 acc = {0.f,0.f,0.f,0.f};
            #pragma unroll
            for (int ks = 0; ks < 4; ++ks){
                f16x8 b = *reinterpret_cast<const f16x8*>(Wih_p + (size_t)(nt*16 + li)*128 + ks*32 + q*8);
                acc = MF(a[ks], b, acc);
            }
            acc_t[j8] = acc;
        }
        #pragma unroll
        for (int r = 0; r < 4; ++r){
            int wr = wbase + r;
            if (wr < NW){
                f16x8 v;
                #pragma unroll
                for (int j8 = 0; j8 < 8; ++j8) v[j8] = (f16)acc_t[j8][r];
                *reinterpret_cast<f16x8*>(xgT + (size_t)wr*512 + li*32 + grp*8) = v;
            }
        }
    }
}

// ---------------- prep: length sort + per-stream sorted event lists ----------------
__device__ __forceinline__ void add_ev(int* et, int* es, int& n, int t, int slot, int len){
    if (t < 0 || t >= len) return;
    int p = n++;
    while (p > 0 && et[p-1] > t){ et[p] = et[p-1]; es[p] = es[p-1]; --p; }
    et[p] = t; es[p] = slot;
}

__global__ void sched_kernel(const int* __restrict__ len_t, const int* __restrict__ len_a, const int* __restrict__ len_f,
                             const int* __restrict__ sub_ta, const int* __restrict__ sub_tf,
                             const int* __restrict__ sub_a, const int* __restrict__ sub_f,
                             int* __restrict__ order, int* __restrict__ slen,
                             int* __restrict__ ev_t, int* __restrict__ ev_slot, int* __restrict__ nev)
{
    __shared__ int L[768];
    int s = threadIdx.x;              // 0..767, stream id = e*256 + b
    int e = s >> 8, b = s & 255;
    int len = (e==0) ? len_t[b] : (e==1) ? len_a[b] : len_f[b];
    L[s] = len;
    __syncthreads();
    int rank = 0;
    for (int i = 0; i < 768; ++i){
        int li = L[i];
        rank += (li > len) || (li == len && i < s);
    }
    order[rank] = s;                  // descending by length, bijective
    slen[s] = len;

    int et[NEV], es[NEV]; int n = 0;
    if (e == 0){
        for (int r = 0; r < 10; ++r){
            add_ev(et, es, n, sub_ta[b*10+r]-1, b*10+r,        len);
            add_ev(et, es, n, sub_tf[b*10+r]-1, 2560 + b*10+r, len);
        }
    } else if (e == 1){
        for (int r = 0; r < 10; ++r) add_ev(et, es, n, sub_a[b*10+r]-1, 5120 + b*10+r, len);
    } else {
        for (int r = 0; r < 10; ++r) add_ev(et, es, n, sub_f[b*10+r]-1, 7680 + b*10+r, len);
    }
    add_ev(et, es, n, len-1, 10240 + s, len);   // final hidden state
    nev[s] = n;
    for (int i = 0; i < n; ++i){ ev_t[s*NEV+i] = et[i]; ev_slot[s*NEV+i] = es[i]; }
}

// ---------------- main LSTM: 8 uniform waves, independent MFMAs, per-lane 4-deep global prefetch ----------------
__launch_bounds__(512, 2)
__global__ void lstm_kernel(const float* __restrict__ gps0, const float* __restrict__ gps1, const float* __restrict__ gps2,
                            const int* __restrict__ grid0, const int* __restrict__ grid1, const int* __restrict__ grid2,
                            const f16* __restrict__ xgT, const f16* __restrict__ Whh_p,
                            const float* __restrict__ Wg_o, const float* __restrict__ bsum_o,
                            const int* __restrict__ order, const int* __restrict__ slen,
                            const int* __restrict__ ev_t, const int* __restrict__ ev_slot, const int* __restrict__ nev,
                            float* __restrict__ stash)
{
    __shared__ f16 A_s[2][4][SROWH];   // h per stream (rows 0..2), row 3 zero; double-buffered
    __shared__ int ev_t_s[3][NEV];
    __shared__ int ev_sl_s[3][NEV];

    const int tid  = threadIdx.x;
    const int lane = tid & 63;
    const int wv   = tid >> 6;          // 0..7, all identical roles
    const int q    = lane >> 4;         // quarter: stream (q<3) / k-group
    const int li   = lane & 15;
    const int u    = (wv << 4) + li;    // unit 0..127
    const int qc   = (q < 3) ? q : 2;
    const int bi   = blockIdx.x;

    const int s0 = order[bi], s1 = order[bi+256], s2 = order[bi+512];
    const int l0 = slen[s0], l1 = slen[s1], l2 = slen[s2];
    int maxlen = l0 > l1 ? l0 : l1; if (l2 > maxlen) maxlen = l2;

    // ---- init LDS ----
    for (int i = tid; i < 2*4*SROWH; i += 512) (&A_s[0][0][0])[i] = (f16)0.f;
    if (tid < 72){
        int m = tid / NEV, i = tid % NEV;
        int sm = (m==0) ? s0 : (m==1) ? s1 : s2;
        ev_t_s[m][i]  = ev_t[sm*NEV + i];
        ev_sl_s[m][i] = ev_slot[sm*NEV + i];
    }

    // ---- weights resident: wave wv owns units [wv*16, wv*16+16), 4 gates, K=128 ----
    f16x8 wI[4], wF[4], wG[4], wO[4];
    {
        const int kg = q << 3;
        #pragma unroll
        for (int ks = 0; ks < 4; ++ks){
            const int koff = ks*32 + kg;
            wI[ks] = *reinterpret_cast<const f16x8*>(Whh_p + (size_t)(  0 + u) * 128 + koff);
            wF[ks] = *reinterpret_cast<const f16x8*>(Whh_p + (size_t)(128 + u) * 128 + koff);
            wG[ks] = *reinterpret_cast<const f16x8*>(Whh_p + (size_t)(256 + u) * 128 + koff);
            wO[ks] = *reinterpret_cast<const f16x8*>(Whh_p + (size_t)(384 + u) * 128 + koff);
        }
    }
    // per-lane gate-base params (p-order: 4 gates of unit u at p = u*4..u*4+3)
    f32x4 bs4 = *reinterpret_cast<const f32x4*>(bsum_o + (u << 2));
    float wgx4[4], wgy4[4];
    {
        f32x4 w0 = *reinterpret_cast<const f32x4*>(Wg_o + (u << 3));
        f32x4 w1 = *reinterpret_cast<const f32x4*>(Wg_o + (u << 3) + 4);
        wgx4[0]=w0[0]; wgy4[0]=w0[1]; wgx4[1]=w0[2]; wgy4[1]=w0[3];
        wgx4[2]=w1[0]; wgy4[2]=w1[1]; wgx4[3]=w1[2]; wgy4[3]=w1[3];
    }

    // ---- per-lane stream state ----
    const int sq = (qc==0)?s0:(qc==1)?s1:s2;
    const float* gps_q  = (((sq>>8)==0) ? gps0 : ((sq>>8)==1) ? gps1 : gps2) + (size_t)(sq&255)*(TT*2);
    const int*   grid_q = (((sq>>8)==0) ? grid0 : ((sq>>8)==1) ? grid1 : grid2) + (size_t)(sq&255)*TT;
    float creg = 0.f, hreg = 0.f;
    int len_q = 0, nev_q = 0, evp = 0, next_t = 1<<30;
    if (q < 3){
        len_q = (q==0)?l0:(q==1)?l1:l2;
        nev_q = nev[sq];
    }

    // ---- 4-deep static prefetch pipelines (per lane) ----
    f16x4 xga[4];
    int   idg[4];
    float gpx[4], gpy[4];
    {
        #pragma unroll
        for (int f = 0; f < 4; ++f){
            int wd = grid_q[f];
            xga[f] = *reinterpret_cast<const f16x4*>(xgT + (size_t)wd*512 + (u << 2));
            idg[f] = grid_q[f + 4];
            float2 gg = *reinterpret_cast<const float2*>(gps_q + f*2);
            gpx[f] = gg.x; gpy[f] = gg.y;
        }
    }

    __syncthreads();   // LDS zero-init + ev lists visible
    if (q < 3 && nev_q > 0) next_t = ev_t_s[qc][0];

#define STEP(T, P, P1, F)                                                                   \
{                                                                                           \
    f16x8 av[4];                                                                            \
    {                                                                                       \
        const f16* Arow = &A_s[P][li >> 2][q << 3];                                         \
        _Pragma("unroll")                                                                   \
        for (int ks = 0; ks < 4; ++ks)                                                      \
            av[ks] = *reinterpret_cast<const f16x8*>(Arow + ks*32);                         \
    }                                                                                       \
    /* consume prefetched gate base */                                                      \
    float baseg[4];                                                                         \
    {                                                                                       \
        f16x4 xv = xga[F];                                                                  \
        const float gx = gpx[F], gy = gpy[F];                                               \
        _Pragma("unroll")                                                                   \
        for (int g = 0; g < 4; ++g)                                                         \
            baseg[g] = (float)xv[g] + bs4[g] + gx*wgx4[g] + gy*wgy4[g];                     \
    }                                                                                       \
    /* refill pipelines (4 steps of slack) */                                               \
    xga[F] = *reinterpret_cast<const f16x4*>(xgT + (size_t)idg[F]*512 + (u << 2));          \
    {                                                                                       \
        int t8 = (T)+8; if (t8 > TT-1) t8 = TT-1;                                           \
        idg[F] = grid_q[t8];                                                                \
        int t4 = (T)+4; if (t4 > TT-1) t4 = TT-1;                                           \
        float2 gg = *reinterpret_cast<const float2*>(gps_q + (size_t)t4*2);                 \
        gpx[F] = gg.x; gpy[F] = gg.y;                                                       \
    }                                                                                       \
    /* 16 independent MFMAs: acc[gate][ks], C = 0 */                                        \
    f32x4 aI[4], aF[4], aG[4], aO[4];                                                       \
    _Pragma("unroll")                                                                       \
    for (int ks = 0; ks < 4; ++ks){                                                         \
        f32x4 z = {0.f,0.f,0.f,0.f};                                                        \
        aI[ks] = MF(av[ks], wI[ks], z);                                                     \
        aF[ks] = MF(av[ks], wF[ks], z);                                                     \
        aG[ks] = MF(av[ks], wG[ks], z);                                                     \
        aO[ks] = MF(av[ks], wO[ks], z);                                                     \
    }                                                                                       \
    if (q < 3){                                                                             \
        float gI = (aI[0][0] + aI[1][0]) + (aI[2][0] + aI[3][0]) + baseg[0];                \
        float gF = (aF[0][0] + aF[1][0]) + (aF[2][0] + aF[3][0]) + baseg[1];                \
        float gG = (aG[0][0] + aG[1][0]) + (aG[2][0] + aG[3][0]) + baseg[2];                \
        float gO = (aO[0][0] + aO[1][0]) + (aO[2][0] + aO[3][0]) + baseg[3];                \
        if ((T) < len_q){                                                                   \
            float si = sigm(gI), sf = sigm(gF), so = sigm(gO);                              \
            float tg = tanh_f(gG);                                                          \
            creg = sf * creg + si * tg;                                                     \
            hreg = so * tanh_f(creg);                                                       \
            while ((T) == next_t){                                                          \
                stash[(size_t)ev_sl_s[qc][evp]*HH + u] = hreg;                              \
                ++evp;                                                                      \
                next_t = (evp < nev_q) ? ev_t_s[qc][evp] : (1<<30);                         \
            }                                                                               \
        }                                                                                   \
        A_s[P1][q][u] = (f16)hreg;                                                          \
    }                                                                                       \
    asm volatile("s_waitcnt lgkmcnt(0)" ::: "memory");                                      \
    __builtin_amdgcn_s_barrier();                                                           \
    asm volatile("" ::: "memory");                                                          \
}

    int t = 0;
    for (; t + 3 < maxlen; t += 4){
        STEP(t,   0, 1, 0);
        STEP(t+1, 1, 0, 1);
        STEP(t+2, 0, 1, 2);
        STEP(t+3, 1, 0, 3);
    }
    if (t < maxlen)     STEP(t,   0, 1, 0);
    if (t+1 < maxlen)   STEP(t+1, 1, 0, 1);
    if (t+2 < maxlen)   STEP(t+2, 0, 1, 2);
#undef STEP
}

// ---------------- fsim applied in-place on the stash (fp32, LDS-staged transposed weights) ----------------
__global__ void fsim_kernel(float* __restrict__ stash, const float* __restrict__ WT,
                            const float* __restrict__ bi, const float* __restrict__ bc, const float* __restrict__ bo,
                            const int* __restrict__ sub_ta, const int* __restrict__ sub_tf,
                            const int* __restrict__ sub_a, const int* __restrict__ sub_f,
                            const int* __restrict__ len_t, const int* __restrict__ len_a, const int* __restrict__ len_f)
{
    __shared__ float h_s[64][HH];
    __shared__ float w_s[3][32][HH];
    const int tid = threadIdx.x;
    const int base = blockIdx.x * 64;

    for (int i = tid; i < 64*HH; i += 256){
        int v = i >> 7, k = i & 127;
        int row = base + v;
        bool valid = true;
        if (row < 10240){
            int g = row / 2560, rr = row % 2560, b = rr / 10;
            int sub, len;
            if (g == 0){ sub = sub_ta[rr]; len = len_t[b]; }
            else if (g == 1){ sub = sub_tf[rr]; len = len_t[b]; }
            else if (g == 2){ sub = sub_a[rr]; len = len_a[b]; }
            else { sub = sub_f[rr]; len = len_f[b]; }
            valid = (sub - 1) < len;    // y is zero past length
        }
        h_s[v][k] = valid ? stash[(size_t)row * HH + k] : 0.f;
    }
    __syncthreads();

    const int uu = tid & 127;
    const int vb = (tid >> 7) << 5;
    float aI[32], aC[32], aO[32];
    #pragma unroll
    for (int v = 0; v < 32; ++v){ aI[v]=0.f; aC[v]=0.f; aO[v]=0.f; }

    for (int kc = 0; kc < 4; ++kc){
        for (int i = tid; i < 3*32*HH; i += 256){
            int w = i >> 12, rem = i & 4095, kk = rem >> 7, u2 = rem & 127;
            w_s[w][kk][u2] = WT[(size_t)w*16384 + (size_t)(kc*32 + kk)*HH + u2];
        }
        __syncthreads();
        for (int kk = 0; kk < 32; ++kk){
            float wi = w_s[0][kk][uu], wc = w_s[1][kk][uu], wo = w_s[2][kk][uu];
            #pragma unroll
            for (int v = 0; v < 32; ++v){
                float h = h_s[vb + v][kc*32 + kk];
                aI[v] = fmaf(h, wi, aI[v]);
                aC[v] = fmaf(h, wc, aC[v]);
                aO[v] = fmaf(h, wo, aO[v]);
            }
        }
        __syncthreads();
    }
    float BI = bi[uu], BC = bc[uu], BO = bo[uu];
    #pragma unroll
    for (int v = 0; v < 32; ++v){
        float C   = sigm(aI[v] + BI) * tanh_f(aC[v] + BC);
        float out = sigm(aO[v] + BO) * tanh_f(C) + h_s[vb + v][uu];
        stash[(size_t)(base + vb + v) * HH + uu] = out;
    }
}

// ---------------- distances: out = exp(-||u - v||) ----------------
__global__ void dist_kernel(const float* __restrict__ fs, float* __restrict__ out)
{
    int gid = blockIdx.x * 256 + threadIdx.x;
    int pair = gid >> 6, ln = gid & 63;
    if (pair >= 5632) return;
    int ia, ib;
    if (pair < 256){ ia = 10240 + pair; ib = 10240 + 256 + pair; }
    else if (pair < 512){ int j = pair - 256; ia = 10240 + j; ib = 10240 + 512 + j; }
    else if (pair < 3072){ int j = pair - 512; ia = j; ib = 5120 + j; }
    else { int j = pair - 3072; ia = 2560 + j; ib = 7680 + j; }
    float d = 0.f;
    #pragma unroll
    for (int k = 0; k < 2; ++k){
        int kk = ln + k*64;
        float df = fs[(size_t)ia*HH + kk] - fs[(size_t)ib*HH + kk];
        d = fmaf(df, df, d);
    }
    #pragma unroll
    for (int off = 32; off > 0; off >>= 1) d += __shfl_xor(d, off);
    if (ln == 0) out[pair] = __expf(-sqrtf(d));
}

extern "C" void kernel_launch(void* const* d_in, const int* in_sizes, int n_in,
                              void* d_out, int out_size, void* d_ws, size_t ws_size,
                              hipStream_t stream)
{
    (void)n_in; (void)out_size; (void)ws_size;
    const float* traj_gps = (const float*)d_in[0];
    const int*   traj_grid = (const int*)d_in[2];
    const int*   traj_len = (const int*)d_in[4];
    const int*   sub_ta = (const int*)d_in[5];
    const int*   sub_tf = (const int*)d_in[6];
    const float* anc_gps = (const float*)d_in[7];
    const int*   anc_grid = (const int*)d_in[9];
    const int*   anc_len = (const int*)d_in[11];
    const int*   sub_a = (const int*)d_in[12];
    const float* far_gps = (const float*)d_in[13];
    const int*   far_grid = (const int*)d_in[15];
    const int*   far_len = (const int*)d_in[17];
    const int*   sub_f = (const int*)d_in[18];
    const float* E    = (const float*)d_in[19];
    const float* W_ih = (const float*)d_in[20];
    const float* W_hh = (const float*)d_in[21];
    const float* b_ih = (const float*)d_in[22];
    const float* b_hh = (const float*)d_in[23];
    const float* Wi = (const float*)d_in[24];
    const float* bi = (const float*)d_in[25];
    const float* Wc = (const float*)d_in[26];
    const float* bc = (const float*)d_in[27];
    const float* Wo = (const float*)d_in[28];
    const float* bo = (const float*)d_in[29];

    const int NW_rt = in_sizes[19] / HH;   // 50000

    char* p = (char*)d_ws;
    f16* Whh_p    = (f16*)p;   p += (size_t)512*128*2;
    f16* Wih_p    = (f16*)p;   p += (size_t)512*128*2;
    float* Wg_o   = (float*)p; p += 1024*4;
    float* bsum_o = (float*)p; p += 512*4;
    float* WT     = (float*)p; p += (size_t)3*128*128*4;
    int* order    = (int*)p;   p += 768*4;
    int* slen     = (int*)p;   p += 768*4;
    int* ev_t     = (int*)p;   p += 768*NEV*4;
    int* ev_slot  = (int*)p;   p += 768*NEV*4;
    int* nev      = (int*)p;   p += 768*4;
    float* stash  = (float*)p; p += (size_t)11008*128*4;
    f16* xgT      = (f16*)p;   p += (size_t)NW_rt*512*2;

    pack_kernel<<<576, 256, 0, stream>>>(W_ih, W_hh, b_ih, b_hh, Wi, Wc, Wo,
                                         Whh_p, Wih_p, Wg_o, bsum_o, WT);
    xg_gemm<<<(NW_rt + 127)/128, 512, 0, stream>>>(E, Wih_p, xgT, NW_rt);
    sched_kernel<<<1, 768, 0, stream>>>(traj_len, anc_len, far_len, sub_ta, sub_tf, sub_a, sub_f,
                                        order, slen, ev_t, ev_slot, nev);
    lstm_kernel<<<256, 512, 0, stream>>>(traj_gps, anc_gps, far_gps, traj_grid, anc_grid, far_grid,
                                         xgT, Whh_p, Wg_o, bsum_o, order, slen, ev_t, ev_slot, nev, stash);
    fsim_kernel<<<172, 256, 0, stream>>>(stash, WT, bi, bc, bo, sub_ta, sub_tf, sub_a, sub_f,
                                         traj_len, anc_len, far_len);
    dist_kernel<<<1408, 256, 0, stream>>>(stash, (float*)d_out);
}

// Round 9
// 931.068 us; speedup vs baseline: 1.6430x; 1.2721x over previous
//
#include <hip/hip_runtime.h>
#include <math.h>

typedef _Float16 f16;
typedef _Float16 f16x8 __attribute__((ext_vector_type(8)));
typedef _Float16 f16x4 __attribute__((ext_vector_type(4)));
typedef float f32x4 __attribute__((ext_vector_type(4)));

#define TT 1024
#define HH 128
#define SROWH 144
#define NEV 24

#define S_SIG  (-1.4426950408889634f)
#define S_TANH (2.8853900817779268f)

__device__ __forceinline__ float rcp_f(float x){ return __builtin_amdgcn_rcpf(x); }
__device__ __forceinline__ float exp2_f(float x){ return __builtin_amdgcn_exp2f(x); }

#define MF(a,b,c) __builtin_amdgcn_mfma_f32_16x16x32_f16((a),(b),(c),0,0,0)

__device__ __forceinline__ void gload_lds16(const void* g, void* l){
    __builtin_amdgcn_global_load_lds((const __attribute__((address_space(1))) void*)g,
                                     (__attribute__((address_space(3))) void*)l, 16, 0, 0);
}

// ---------------- prep ----------------
// Whh_p: f16 W_hh rows j = g*128+u, scaled per-gate (i,f,o: -log2e; g: 2*log2e)
// Wih_p: xg_gemm tiling rows j = nt*16+li_w hold W_ih row (g*128+u), p = li_w*32+nt = u*4+g (UNscaled; scaled at xg store)
// Wg_o[p][c] scaled; bsum_o[p] unscaled (consumed+scaled in xg_gemm)
__global__ void pack_kernel(const float* __restrict__ W_ih, const float* __restrict__ W_hh,
                            const float* __restrict__ b_ih, const float* __restrict__ b_hh,
                            const float* __restrict__ Wi, const float* __restrict__ Wc, const float* __restrict__ Wo,
                            f16* __restrict__ Whh_p, f16* __restrict__ Wih_p,
                            float* __restrict__ Wg_o, float* __restrict__ bsum_o, float* __restrict__ WT)
{
    const float scl[4] = {S_SIG, S_SIG, S_TANH, S_SIG};
    int idx = blockIdx.x*256 + threadIdx.x;
    if (idx < 512*128){
        int j = idx >> 7;
        Whh_p[idx] = (f16)(W_hh[idx] * scl[j >> 7]);
        int k = idx & 127;
        int p = ((j & 15) << 5) + (j >> 4);   // li_w*32 + nt
        int u = p >> 2, g = p & 3;
        Wih_p[idx] = (f16)W_ih[(g*128 + u)*130 + k];
    }
    if (idx < 1024){
        int p = idx >> 1, c = idx & 1;
        int u = p >> 2, g = p & 3;
        Wg_o[idx] = W_ih[(g*128 + u)*130 + 128 + c] * scl[g];
    }
    if (idx < 512){
        int u = idx >> 2, g = idx & 3;
        bsum_o[idx] = b_ih[g*128 + u] + b_hh[g*128 + u];
    }
    if (idx < 3*128*128){
        int w = idx >> 14, rem = idx & 16383, k = rem >> 7, u = rem & 127;
        const float* W = (w==0) ? Wi : (w==1) ? Wc : Wo;
        WT[idx] = W[u*128 + k];   // WT[w][k][u] = W[u][k]
    }
}

// ---------------- precompute xgT[word][p] = scl[g]*(E0[word].W_ih^T + bias), f16, p-order ----------------
__global__ void xg_gemm(const float* __restrict__ E, const f16* __restrict__ Wih_p,
                        const float* __restrict__ bsum_o, f16* __restrict__ xgT, int NW)
{
    const float scl[4] = {S_SIG, S_SIG, S_TANH, S_SIG};
    const int w = threadIdx.x >> 6, lane = threadIdx.x & 63;
    const int li = lane & 15, q = lane >> 4;
    const int word = blockIdx.x*128 + w*16 + li;

    f16x8 a[4];
    const bool valid = (word > 0) && (word < NW);
    #pragma unroll
    for (int ks = 0; ks < 4; ++ks){
        f32x4 v0 = {0.f,0.f,0.f,0.f}, v1 = v0;
        if (valid){
            const f32x4* Er = (const f32x4*)(E + (size_t)word*HH);
            v0 = Er[ks*8 + q*2];
            v1 = Er[ks*8 + q*2 + 1];
        }
        f16x8 t;
        t[0]=(f16)v0[0]; t[1]=(f16)v0[1]; t[2]=(f16)v0[2]; t[3]=(f16)v0[3];
        t[4]=(f16)v1[0]; t[5]=(f16)v1[1]; t[6]=(f16)v1[2]; t[7]=(f16)v1[3];
        a[ks] = t;
    }
    const int wbase = blockIdx.x*128 + w*16 + q*4;
    #pragma unroll
    for (int grp = 0; grp < 4; ++grp){
        f32x4 acc_t[8];
        #pragma unroll
        for (int j8 = 0; j8 < 8; ++j8){
            const int nt = grp*8 + j8;
            f32x4 acc = {0.f,0.f,0.f,0.f};
            #pragma unroll
            for (int ks = 0; ks < 4; ++ks){
                f16x8 b = *reinterpret_cast<const f16x8*>(Wih_p + (size_t)(nt*16 + li)*128 + ks*32 + q*8);
                acc = MF(a[ks], b, acc);
            }
            acc_t[j8] = acc;
        }
        f32x4 bb0 = *reinterpret_cast<const f32x4*>(bsum_o + li*32 + grp*8);
        f32x4 bb1 = *reinterpret_cast<const f32x4*>(bsum_o + li*32 + grp*8 + 4);
        #pragma unroll
        for (int r = 0; r < 4; ++r){
            int wr = wbase + r;
            if (wr < NW){
                f16x8 v;
                #pragma unroll
                for (int j8 = 0; j8 < 8; ++j8){
                    float bias = (j8 < 4) ? bb0[j8] : bb1[j8-4];
                    v[j8] = (f16)((acc_t[j8][r] + bias) * scl[j8 & 3]);
                }
                *reinterpret_cast<f16x8*>(xgT + (size_t)wr*512 + li*32 + grp*8) = v;
            }
        }
    }
}

// ---------------- prep: length sort + per-stream sorted event lists ----------------
__device__ __forceinline__ void add_ev(int* et, int* es, int& n, int t, int slot, int len){
    if (t < 0 || t >= len) return;
    int p = n++;
    while (p > 0 && et[p-1] > t){ et[p] = et[p-1]; es[p] = es[p-1]; --p; }
    et[p] = t; es[p] = slot;
}

__global__ void sched_kernel(const int* __restrict__ len_t, const int* __restrict__ len_a, const int* __restrict__ len_f,
                             const int* __restrict__ sub_ta, const int* __restrict__ sub_tf,
                             const int* __restrict__ sub_a, const int* __restrict__ sub_f,
                             int* __restrict__ order, int* __restrict__ slen,
                             int* __restrict__ ev_t, int* __restrict__ ev_slot, int* __restrict__ nev)
{
    __shared__ int L[768];
    int s = threadIdx.x;              // 0..767, stream id = e*256 + b
    int e = s >> 8, b = s & 255;
    int len = (e==0) ? len_t[b] : (e==1) ? len_a[b] : len_f[b];
    L[s] = len;
    __syncthreads();
    int rank = 0;
    for (int i = 0; i < 768; ++i){
        int li = L[i];
        rank += (li > len) || (li == len && i < s);
    }
    order[rank] = s;                  // descending by length, bijective
    slen[s] = len;

    int et[NEV], es[NEV]; int n = 0;
    if (e == 0){
        for (int r = 0; r < 10; ++r){
            add_ev(et, es, n, sub_ta[b*10+r]-1, b*10+r,        len);
            add_ev(et, es, n, sub_tf[b*10+r]-1, 2560 + b*10+r, len);
        }
    } else if (e == 1){
        for (int r = 0; r < 10; ++r) add_ev(et, es, n, sub_a[b*10+r]-1, 5120 + b*10+r, len);
    } else {
        for (int r = 0; r < 10; ++r) add_ev(et, es, n, sub_f[b*10+r]-1, 7680 + b*10+r, len);
    }
    add_ev(et, es, n, len-1, 10240 + s, len);   // final hidden state
    nev[s] = n;
    for (int i = 0; i < n; ++i){ ev_t[s*NEV+i] = et[i]; ev_slot[s*NEV+i] = es[i]; }
}

// ---------------- main LSTM: 8 uniform waves; LDS ring staged by global_load_lds; exp2-folded nonlin ----------------
__launch_bounds__(512, 2)
__global__ void lstm_kernel(const float* __restrict__ gps0, const float* __restrict__ gps1, const float* __restrict__ gps2,
                            const int* __restrict__ grid0, const int* __restrict__ grid1, const int* __restrict__ grid2,
                            const f16* __restrict__ xgT, const f16* __restrict__ Whh_p,
                            const float* __restrict__ Wg_o,
                            const int* __restrict__ order, const int* __restrict__ slen,
                            const int* __restrict__ ev_t, const int* __restrict__ ev_slot, const int* __restrict__ nev,
                            float* __restrict__ stash)
{
    __shared__ f16   A_s[2][4][SROWH];   // h per stream (rows 0..2), row 3 zero; double-buffered
    __shared__ f16   ring[16][3][512];   // 16-step ring of folded gate bases (scaled xg+bias), staged 8 ahead
    __shared__ float gpr[16][3][2];      // gps pairs ring
    __shared__ int   gring[16][4];       // grid-index ring (stream-padded)
    __shared__ int   ev_t_s[3][NEV];
    __shared__ int   ev_sl_s[3][NEV];

    const int tid  = threadIdx.x;
    const int lane = tid & 63;
    const int wv   = tid >> 6;          // 0..7, uniform roles
    const int q    = lane >> 4;
    const int li   = lane & 15;
    const int u    = (wv << 4) + li;    // unit 0..127
    const int qc   = (q < 3) ? q : 2;
    const int bi   = blockIdx.x;

    const int s0 = order[bi], s1 = order[bi+256], s2 = order[bi+512];
    const int l0 = slen[s0], l1 = slen[s1], l2 = slen[s2];
    int maxlen = l0 > l1 ? l0 : l1; if (l2 > maxlen) maxlen = l2;

    // stream pointers (all lanes)
    const int e0=s0>>8, b0=s0&255, e1=s1>>8, b1=s1&255, e2=s2>>8, b2=s2&255;
    const int* g0p = ((e0==0)?grid0:(e0==1)?grid1:grid2) + (size_t)b0*TT;
    const int* g1p = ((e1==0)?grid0:(e1==1)?grid1:grid2) + (size_t)b1*TT;
    const int* g2p = ((e2==0)?grid0:(e2==1)?grid1:grid2) + (size_t)b2*TT;
    const float* q0p = ((e0==0)?gps0:(e0==1)?gps1:gps2) + (size_t)b0*(TT*2);
    const float* q1p = ((e1==0)?gps0:(e1==1)?gps1:gps2) + (size_t)b1*(TT*2);
    const float* q2p = ((e2==0)?gps0:(e2==1)?gps1:gps2) + (size_t)b2*(TT*2);

    // ---- init LDS ----
    for (int i = tid; i < 2*4*SROWH; i += 512) (&A_s[0][0][0])[i] = (f16)0.f;
    if (tid < 72){
        int m = tid / NEV, i = tid % NEV;
        int sm = (m==0) ? s0 : (m==1) ? s1 : s2;
        ev_t_s[m][i]  = ev_t[sm*NEV + i];
        ev_sl_s[m][i] = ev_slot[sm*NEV + i];
    }

    // ---- resident weights (pre-scaled) ----
    f16x8 wI[4], wF[4], wG[4], wO[4];
    {
        const int kg = q << 3;
        #pragma unroll
        for (int ks = 0; ks < 4; ++ks){
            const int koff = ks*32 + kg;
            wI[ks] = *reinterpret_cast<const f16x8*>(Whh_p + (size_t)(  0 + u) * 128 + koff);
            wF[ks] = *reinterpret_cast<const f16x8*>(Whh_p + (size_t)(128 + u) * 128 + koff);
            wG[ks] = *reinterpret_cast<const f16x8*>(Whh_p + (size_t)(256 + u) * 128 + koff);
            wO[ks] = *reinterpret_cast<const f16x8*>(Whh_p + (size_t)(384 + u) * 128 + koff);
        }
    }
    float wgx4[4], wgy4[4];
    {
        f32x4 w0 = *reinterpret_cast<const f32x4*>(Wg_o + (u << 3));
        f32x4 w1 = *reinterpret_cast<const f32x4*>(Wg_o + (u << 3) + 4);
        wgx4[0]=w0[0]; wgy4[0]=w0[1]; wgx4[1]=w0[2]; wgy4[1]=w0[3];
        wgx4[2]=w1[0]; wgy4[2]=w1[1]; wgx4[3]=w1[2]; wgy4[3]=w1[3];
    }

    // per-lane stream state
    float creg = 0.f, hreg = 0.f;
    int len_q = 0, nev_q = 0, evp = 0, next_t = 1<<30;
    if (q < 3){
        int sq = (q==0)?s0:(q==1)?s1:s2;
        len_q = (q==0)?l0:(q==1)?l1:l2;
        nev_q = nev[sq];
    }
    // staging-duty lane-fixed pointers
    const float* sgps = ((lane>>4)==0) ? q0p : ((lane>>4)==1) ? q1p : q2p;
    const int*   sgrd = ((lane>>3)==0) ? g0p : ((lane>>3)==1) ? g1p : g2p;

    // ---- prologue: prime ring slots 0..7, gpr 0..7, gring 8..15 ----
    {
        int wa = g0p[wv], wb = g1p[wv], wc = g2p[wv];
        gload_lds16(xgT + (size_t)wa*512 + (lane<<3), &ring[wv][0][0]);
        gload_lds16(xgT + (size_t)wb*512 + (lane<<3), &ring[wv][1][0]);
        gload_lds16(xgT + (size_t)wc*512 + (lane<<3), &ring[wv][2][0]);
    }
    if (tid < 48){
        int sm = tid >> 4, i = tid & 15;
        gpr[i>>1][sm][i&1] = ((sm==0)?q0p:(sm==1)?q1p:q2p)[i];
    }
    if (tid < 24){
        int sm = tid >> 3, i = tid & 7;
        gring[8+i][sm] = ((sm==0)?g0p:(sm==1)?g1p:g2p)[8+i];
    }
    __syncthreads();   // drains vmcnt(0)+lgkmcnt(0): ring slots 0..7 landed
    if (q < 3 && nev_q > 0) next_t = ev_t_s[qc][0];

#define STEP(T, P, P1, K)                                                                   \
{                                                                                           \
    f16x8 av[4];                                                                            \
    {                                                                                       \
        const f16* Arow = &A_s[P][li >> 2][q << 3];                                         \
        av[0] = *reinterpret_cast<const f16x8*>(Arow);                                      \
        av[1] = *reinterpret_cast<const f16x8*>(Arow + 32);                                 \
        av[2] = *reinterpret_cast<const f16x8*>(Arow + 64);                                 \
        av[3] = *reinterpret_cast<const f16x8*>(Arow + 96);                                 \
    }                                                                                       \
    const f16x4 xv = *reinterpret_cast<const f16x4*>(&ring[K][qc][u << 2]);                 \
    const float2 gp = *reinterpret_cast<const float2*>(&gpr[K][qc][0]);                     \
    if (((K) & 7) == 0){                                                                    \
        const int tb = ((K) + 8) & 15;                                                      \
        const int tsl = tb + wv;                                                            \
        int wd0 = gring[tsl][0];                                                            \
        int wd1 = gring[tsl][1];                                                            \
        int wd2 = gring[tsl][2];                                                            \
        gload_lds16(xgT + (size_t)wd0*512 + (lane<<3), &ring[tsl][0][0]);                   \
        gload_lds16(xgT + (size_t)wd1*512 + (lane<<3), &ring[tsl][1][0]);                   \
        gload_lds16(xgT + (size_t)wd2*512 + (lane<<3), &ring[tsl][2][0]);                   \
        if (wv == 6 && lane < 48){                                                          \
            int i2 = lane & 15, sm = lane >> 4;                                             \
            int tp = (T) + 8 + (i2 >> 1); if (tp > TT-1) tp = TT-1;                         \
            gpr[tb + (i2 >> 1)][sm][i2 & 1] = sgps[(size_t)tp*2 + (i2 & 1)];                \
        }                                                                                   \
        if (wv == 7 && lane < 24){                                                          \
            int i2 = lane & 7, sm = lane >> 3;                                              \
            int tp = (T) + 16 + i2; if (tp > TT-1) tp = TT-1;                               \
            gring[((K) & 8) + i2][sm] = sgrd[tp];                                           \
        }                                                                                   \
    }                                                                                       \
    const f32x4 zz = {0.f,0.f,0.f,0.f};                                                     \
    f32x4 iA = MF(av[1], wI[1], MF(av[0], wI[0], zz));                                      \
    f32x4 iB = MF(av[3], wI[3], MF(av[2], wI[2], zz));                                      \
    f32x4 fA = MF(av[1], wF[1], MF(av[0], wF[0], zz));                                      \
    f32x4 fB = MF(av[3], wF[3], MF(av[2], wF[2], zz));                                      \
    f32x4 gA = MF(av[1], wG[1], MF(av[0], wG[0], zz));                                      \
    f32x4 gB = MF(av[3], wG[3], MF(av[2], wG[2], zz));                                      \
    f32x4 oA = MF(av[1], wO[1], MF(av[0], wO[0], zz));                                      \
    f32x4 oB = MF(av[3], wO[3], MF(av[2], wO[2], zz));                                      \
    if (q < 3){                                                                             \
        float bI = fmaf(gp.y, wgy4[0], fmaf(gp.x, wgx4[0], (float)xv[0]));                  \
        float bF = fmaf(gp.y, wgy4[1], fmaf(gp.x, wgx4[1], (float)xv[1]));                  \
        float bG = fmaf(gp.y, wgy4[2], fmaf(gp.x, wgx4[2], (float)xv[2]));                  \
        float bO = fmaf(gp.y, wgy4[3], fmaf(gp.x, wgx4[3], (float)xv[3]));                  \
        float yI = (iA[0] + iB[0]) + bI;                                                    \
        float yF = (fA[0] + fB[0]) + bF;                                                    \
        float yG = (gA[0] + gB[0]) + bG;                                                    \
        float yO = (oA[0] + oB[0]) + bO;                                                    \
        if ((T) < len_q){                                                                   \
            float si = rcp_f(1.f + exp2_f(yI));                                             \
            float sf = rcp_f(1.f + exp2_f(yF));                                             \
            float so = rcp_f(1.f + exp2_f(yO));                                             \
            float tg = fmaf(-2.f, rcp_f(1.f + exp2_f(yG)), 1.f);                            \
            creg = fmaf(sf, creg, si * tg);                                                 \
            float th = fmaf(-2.f, rcp_f(1.f + exp2_f(S_TANH * creg)), 1.f);                 \
            hreg = so * th;                                                                 \
            while ((T) == next_t){                                                          \
                stash[(size_t)ev_sl_s[qc][evp]*HH + u] = hreg;                              \
                ++evp;                                                                      \
                next_t = (evp < nev_q) ? ev_t_s[qc][evp] : (1<<30);                         \
            }                                                                               \
        }                                                                                   \
        A_s[P1][q][u] = (f16)hreg;                                                          \
    }                                                                                       \
    if (((K) & 7) == 7) asm volatile("s_waitcnt vmcnt(0)" ::: "memory");                    \
    asm volatile("s_waitcnt lgkmcnt(0)" ::: "memory");                                      \
    __builtin_amdgcn_s_barrier();                                                           \
    asm volatile("" ::: "memory");                                                          \
}

    for (int t = 0; t < maxlen; t += 16){
        STEP(t+0,  0,1, 0)  STEP(t+1,  1,0, 1)  STEP(t+2,  0,1, 2)  STEP(t+3,  1,0, 3)
        STEP(t+4,  0,1, 4)  STEP(t+5,  1,0, 5)  STEP(t+6,  0,1, 6)  STEP(t+7,  1,0, 7)
        STEP(t+8,  0,1, 8)  STEP(t+9,  1,0, 9)  STEP(t+10, 0,1,10)  STEP(t+11, 1,0,11)
        STEP(t+12, 0,1,12)  STEP(t+13, 1,0,13)  STEP(t+14, 0,1,14)  STEP(t+15, 1,0,15)
    }
#undef STEP
}

// ---------------- fsim applied in-place on the stash (fp32, LDS-staged transposed weights) ----------------
__device__ __forceinline__ float sigm(float x){ return 1.f/(1.f + __expf(-x)); }
__device__ __forceinline__ float tanh_f(float x){
    float e = __expf(2.f*x);
    return 1.f - 2.f/(e + 1.f);
}

__global__ void fsim_kernel(float* __restrict__ stash, const float* __restrict__ WT,
                            const float* __restrict__ bi, const float* __restrict__ bc, const float* __restrict__ bo,
                            const int* __restrict__ sub_ta, const int* __restrict__ sub_tf,
                            const int* __restrict__ sub_a, const int* __restrict__ sub_f,
                            const int* __restrict__ len_t, const int* __restrict__ len_a, const int* __restrict__ len_f)
{
    __shared__ float h_s[64][HH];
    __shared__ float w_s[3][32][HH];
    const int tid = threadIdx.x;
    const int base = blockIdx.x * 64;

    for (int i = tid; i < 64*HH; i += 256){
        int v = i >> 7, k = i & 127;
        int row = base + v;
        bool valid = true;
        if (row < 10240){
            int g = row / 2560, rr = row % 2560, b = rr / 10;
            int sub, len;
            if (g == 0){ sub = sub_ta[rr]; len = len_t[b]; }
            else if (g == 1){ sub = sub_tf[rr]; len = len_t[b]; }
            else if (g == 2){ sub = sub_a[rr]; len = len_a[b]; }
            else { sub = sub_f[rr]; len = len_f[b]; }
            valid = (sub - 1) < len;    // y is zero past length
        }
        h_s[v][k] = valid ? stash[(size_t)row * HH + k] : 0.f;
    }
    __syncthreads();

    const int uu = tid & 127;
    const int vb = (tid >> 7) << 5;
    float aI[32], aC[32], aO[32];
    #pragma unroll
    for (int v = 0; v < 32; ++v){ aI[v]=0.f; aC[v]=0.f; aO[v]=0.f; }

    for (int kc = 0; kc < 4; ++kc){
        for (int i = tid; i < 3*32*HH; i += 256){
            int w = i >> 12, rem = i & 4095, kk = rem >> 7, u2 = rem & 127;
            w_s[w][kk][u2] = WT[(size_t)w*16384 + (size_t)(kc*32 + kk)*HH + u2];
        }
        __syncthreads();
        for (int kk = 0; kk < 32; ++kk){
            float wi = w_s[0][kk][uu], wc = w_s[1][kk][uu], wo = w_s[2][kk][uu];
            #pragma unroll
            for (int v = 0; v < 32; ++v){
                float h = h_s[vb + v][kc*32 + kk];
                aI[v] = fmaf(h, wi, aI[v]);
                aC[v] = fmaf(h, wc, aC[v]);
                aO[v] = fmaf(h, wo, aO[v]);
            }
        }
        __syncthreads();
    }
    float BI = bi[uu], BC = bc[uu], BO = bo[uu];
    #pragma unroll
    for (int v = 0; v < 32; ++v){
        float C   = sigm(aI[v] + BI) * tanh_f(aC[v] + BC);
        float out = sigm(aO[v] + BO) * tanh_f(C) + h_s[vb + v][uu];
        stash[(size_t)(base + vb + v) * HH + uu] = out;
    }
}

// ---------------- distances: out = exp(-||u - v||) ----------------
__global__ void dist_kernel(const float* __restrict__ fs, float* __restrict__ out)
{
    int gid = blockIdx.x * 256 + threadIdx.x;
    int pair = gid >> 6, ln = gid & 63;
    if (pair >= 5632) return;
    int ia, ib;
    if (pair < 256){ ia = 10240 + pair; ib = 10240 + 256 + pair; }
    else if (pair < 512){ int j = pair - 256; ia = 10240 + j; ib = 10240 + 512 + j; }
    else if (pair < 3072){ int j = pair - 512; ia = j; ib = 5120 + j; }
    else { int j = pair - 3072; ia = 2560 + j; ib = 7680 + j; }
    float d = 0.f;
    #pragma unroll
    for (int k = 0; k < 2; ++k){
        int kk = ln + k*64;
        float df = fs[(size_t)ia*HH + kk] - fs[(size_t)ib*HH + kk];
        d = fmaf(df, df, d);
    }
    #pragma unroll
    for (int off = 32; off > 0; off >>= 1) d += __shfl_xor(d, off);
    if (ln == 0) out[pair] = __expf(-sqrtf(d));
}

extern "C" void kernel_launch(void* const* d_in, const int* in_sizes, int n_in,
                              void* d_out, int out_size, void* d_ws, size_t ws_size,
                              hipStream_t stream)
{
    (void)n_in; (void)out_size; (void)ws_size;
    const float* traj_gps = (const float*)d_in[0];
    const int*   traj_grid = (const int*)d_in[2];
    const int*   traj_len = (const int*)d_in[4];
    const int*   sub_ta = (const int*)d_in[5];
    const int*   sub_tf = (const int*)d_in[6];
    const float* anc_gps = (const float*)d_in[7];
    const int*   anc_grid = (const int*)d_in[9];
    const int*   anc_len = (const int*)d_in[11];
    const int*   sub_a = (const int*)d_in[12];
    const float* far_gps = (const float*)d_in[13];
    const int*   far_grid = (const int*)d_in[15];
    const int*   far_len = (const int*)d_in[17];
    const int*   sub_f = (const int*)d_in[18];
    const float* E    = (const float*)d_in[19];
    const float* W_ih = (const float*)d_in[20];
    const float* W_hh = (const float*)d_in[21];
    const float* b_ih = (const float*)d_in[22];
    const float* b_hh = (const float*)d_in[23];
    const float* Wi = (const float*)d_in[24];
    const float* bi = (const float*)d_in[25];
    const float* Wc = (const float*)d_in[26];
    const float* bc = (const float*)d_in[27];
    const float* Wo = (const float*)d_in[28];
    const float* bo = (const float*)d_in[29];

    const int NW_rt = in_sizes[19] / HH;   // 50000

    char* p = (char*)d_ws;
    f16* Whh_p    = (f16*)p;   p += (size_t)512*128*2;
    f16* Wih_p    = (f16*)p;   p += (size_t)512*128*2;
    float* Wg_o   = (float*)p; p += 1024*4;
    float* bsum_o = (float*)p; p += 512*4;
    float* WT     = (float*)p; p += (size_t)3*128*128*4;
    int* order    = (int*)p;   p += 768*4;
    int* slen     = (int*)p;   p += 768*4;
    int* ev_t     = (int*)p;   p += 768*NEV*4;
    int* ev_slot  = (int*)p;   p += 768*NEV*4;
    int* nev      = (int*)p;   p += 768*4;
    float* stash  = (float*)p; p += (size_t)11008*128*4;
    f16* xgT      = (f16*)p;   p += (size_t)NW_rt*512*2;

    pack_kernel<<<576, 256, 0, stream>>>(W_ih, W_hh, b_ih, b_hh, Wi, Wc, Wo,
                                         Whh_p, Wih_p, Wg_o, bsum_o, WT);
    xg_gemm<<<(NW_rt + 127)/128, 512, 0, stream>>>(E, Wih_p, bsum_o, xgT, NW_rt);
    sched_kernel<<<1, 768, 0, stream>>>(traj_len, anc_len, far_len, sub_ta, sub_tf, sub_a, sub_f,
                                        order, slen, ev_t, ev_slot, nev);
    lstm_kernel<<<256, 512, 0, stream>>>(traj_gps, anc_gps, far_gps, traj_grid, anc_grid, far_grid,
                                         xgT, Whh_p, Wg_o, order, slen, ev_t, ev_slot, nev, stash);
    fsim_kernel<<<172, 256, 0, stream>>>(stash, WT, bi, bc, bo, sub_ta, sub_tf, sub_a, sub_f,
                                         traj_len, anc_len, far_len);
    dist_kernel<<<1408, 256, 0, stream>>>(stash, (float*)d_out);
}

// Round 10
// 658.738 us; speedup vs baseline: 2.3222x; 1.4134x over previous
//
#include <hip/hip_runtime.h>
#include <math.h>

typedef _Float16 f16;
typedef _Float16 f16x8 __attribute__((ext_vector_type(8)));
typedef _Float16 f16x4 __attribute__((ext_vector_type(4)));
typedef float f32x4 __attribute__((ext_vector_type(4)));

#define TT 1024
#define HH 128
#define SROWH 144
#define NEV 24

#define S_SIG  (-1.4426950408889634f)
#define S_TANH (2.8853900817779268f)

__device__ __forceinline__ float rcp_f(float x){ return __builtin_amdgcn_rcpf(x); }
__device__ __forceinline__ float exp2_f(float x){ return __builtin_amdgcn_exp2f(x); }
__device__ __forceinline__ float sigm_e(float x){ return rcp_f(1.f + exp2_f(S_SIG * x)); }      // sigmoid
__device__ __forceinline__ float tanh_e(float x){ return fmaf(-2.f, rcp_f(1.f + exp2_f(S_TANH * x)), 1.f); }

#define MF(a,b,c) __builtin_amdgcn_mfma_f32_16x16x32_f16((a),(b),(c),0,0,0)

__device__ __forceinline__ void gload_lds16(const void* g, void* l){
    __builtin_amdgcn_global_load_lds((const __attribute__((address_space(1))) void*)g,
                                     (__attribute__((address_space(3))) void*)l, 16, 0, 0);
}

// ---------------- prep ----------------
// Whh_p: f16 W_hh rows j = g*128+u, scaled per-gate (i,f,o: -log2e; g: 2*log2e)
// Wih_p: xg_gemm tiling rows j = nt*16+li_w hold W_ih row (g*128+u), p = li_w*32+nt = u*4+g (unscaled)
// Wg_o[p][c] scaled; bsum_o[p] unscaled (consumed+scaled in xg_gemm); Wfs = f16 copies of Wi/Wc/Wo
__global__ void pack_kernel(const float* __restrict__ W_ih, const float* __restrict__ W_hh,
                            const float* __restrict__ b_ih, const float* __restrict__ b_hh,
                            const float* __restrict__ Wi, const float* __restrict__ Wc, const float* __restrict__ Wo,
                            f16* __restrict__ Whh_p, f16* __restrict__ Wih_p,
                            float* __restrict__ Wg_o, float* __restrict__ bsum_o, f16* __restrict__ Wfs)
{
    const float scl[4] = {S_SIG, S_SIG, S_TANH, S_SIG};
    int idx = blockIdx.x*256 + threadIdx.x;
    if (idx < 512*128){
        int j = idx >> 7;
        Whh_p[idx] = (f16)(W_hh[idx] * scl[j >> 7]);
        int k = idx & 127;
        int p = ((j & 15) << 5) + (j >> 4);   // li_w*32 + nt
        int u = p >> 2, g = p & 3;
        Wih_p[idx] = (f16)W_ih[(g*128 + u)*130 + k];
    }
    if (idx < 1024){
        int p = idx >> 1, c = idx & 1;
        int u = p >> 2, g = p & 3;
        Wg_o[idx] = W_ih[(g*128 + u)*130 + 128 + c] * scl[g];
    }
    if (idx < 512){
        int u = idx >> 2, g = idx & 3;
        bsum_o[idx] = b_ih[g*128 + u] + b_hh[g*128 + u];
    }
    if (idx < 3*128*128){
        int w = idx >> 14, rem = idx & 16383;
        const float* W = (w==0) ? Wi : (w==1) ? Wc : Wo;
        Wfs[idx] = (f16)W[rem];   // [w][u_out][k] row-major
    }
}

// ---------------- precompute xgT[word][p] = scl[g]*(E0[word].W_ih^T + bias), f16, p-order ----------------
__global__ void xg_gemm(const float* __restrict__ E, const f16* __restrict__ Wih_p,
                        const float* __restrict__ bsum_o, f16* __restrict__ xgT, int NW)
{
    const float scl[4] = {S_SIG, S_SIG, S_TANH, S_SIG};
    const int w = threadIdx.x >> 6, lane = threadIdx.x & 63;
    const int li = lane & 15, q = lane >> 4;
    const int word = blockIdx.x*128 + w*16 + li;

    f16x8 a[4];
    const bool valid = (word > 0) && (word < NW);
    #pragma unroll
    for (int ks = 0; ks < 4; ++ks){
        f32x4 v0 = {0.f,0.f,0.f,0.f}, v1 = v0;
        if (valid){
            const f32x4* Er = (const f32x4*)(E + (size_t)word*HH);
            v0 = Er[ks*8 + q*2];
            v1 = Er[ks*8 + q*2 + 1];
        }
        f16x8 t;
        t[0]=(f16)v0[0]; t[1]=(f16)v0[1]; t[2]=(f16)v0[2]; t[3]=(f16)v0[3];
        t[4]=(f16)v1[0]; t[5]=(f16)v1[1]; t[6]=(f16)v1[2]; t[7]=(f16)v1[3];
        a[ks] = t;
    }
    const int wbase = blockIdx.x*128 + w*16 + q*4;
    #pragma unroll
    for (int grp = 0; grp < 4; ++grp){
        f32x4 acc_t[8];
        #pragma unroll
        for (int j8 = 0; j8 < 8; ++j8){
            const int nt = grp*8 + j8;
            f32x4 acc = {0.f,0.f,0.f,0.f};
            #pragma unroll
            for (int ks = 0; ks < 4; ++ks){
                f16x8 b = *reinterpret_cast<const f16x8*>(Wih_p + (size_t)(nt*16 + li)*128 + ks*32 + q*8);
                acc = MF(a[ks], b, acc);
            }
            acc_t[j8] = acc;
        }
        f32x4 bb0 = *reinterpret_cast<const f32x4*>(bsum_o + li*32 + grp*8);
        f32x4 bb1 = *reinterpret_cast<const f32x4*>(bsum_o + li*32 + grp*8 + 4);
        #pragma unroll
        for (int r = 0; r < 4; ++r){
            int wr = wbase + r;
            if (wr < NW){
                f16x8 v;
                #pragma unroll
                for (int j8 = 0; j8 < 8; ++j8){
                    float bias = (j8 < 4) ? bb0[j8] : bb1[j8-4];
                    v[j8] = (f16)((acc_t[j8][r] + bias) * scl[j8 & 3]);
                }
                *reinterpret_cast<f16x8*>(xgT + (size_t)wr*512 + li*32 + grp*8) = v;
            }
        }
    }
}

// ---------------- prep: length sort + per-stream event rank-sort (no scratch, fully unrolled) ----------------
__global__ void sched_kernel(const int* __restrict__ len_t, const int* __restrict__ len_a, const int* __restrict__ len_f,
                             const int* __restrict__ sub_ta, const int* __restrict__ sub_tf,
                             const int* __restrict__ sub_a, const int* __restrict__ sub_f,
                             int* __restrict__ order, int* __restrict__ slen,
                             int* __restrict__ ev_t, int* __restrict__ ev_slot, int* __restrict__ nev)
{
    __shared__ int L[768];
    int s = threadIdx.x;              // 0..767, stream id = e*256 + b
    int e = s >> 8, b = s & 255;
    int len = (e==0) ? len_t[b] : (e==1) ? len_a[b] : len_f[b];
    L[s] = len;
    __syncthreads();
    int rank = 0;
    for (int i = 0; i < 768; ++i){
        int li = L[i];
        rank += (li > len) || (li == len && i < s);
    }
    order[rank] = s;                  // descending by length, bijective
    slen[s] = len;

    int tv[21], sl[21];
    #pragma unroll
    for (int i = 0; i < 21; ++i){ tv[i] = -1; sl[i] = 0; }
    if (e == 0){
        #pragma unroll
        for (int r = 0; r < 10; ++r){
            tv[r]    = sub_ta[b*10+r] - 1;  sl[r]    = b*10 + r;
            tv[10+r] = sub_tf[b*10+r] - 1;  sl[10+r] = 2560 + b*10 + r;
        }
    } else if (e == 1){
        #pragma unroll
        for (int r = 0; r < 10; ++r){ tv[r] = sub_a[b*10+r] - 1; sl[r] = 5120 + b*10 + r; }
    } else {
        #pragma unroll
        for (int r = 0; r < 10; ++r){ tv[r] = sub_f[b*10+r] - 1; sl[r] = 7680 + b*10 + r; }
    }
    tv[20] = len - 1; sl[20] = 10240 + s;

    int n = 0;
    #pragma unroll
    for (int i = 0; i < 21; ++i){
        bool vi = (tv[i] >= 0) && (tv[i] < len);
        if (vi){
            int rk = 0;
            #pragma unroll
            for (int j = 0; j < 21; ++j){
                bool vj = (tv[j] >= 0) && (tv[j] < len);
                rk += (vj && ((tv[j] < tv[i]) || (tv[j] == tv[i] && j < i))) ? 1 : 0;
            }
            ev_t[s*NEV + rk]    = tv[i];
            ev_slot[s*NEV + rk] = sl[i];
            ++n;
        }
    }
    nev[s] = n;
}

// ---------------- main LSTM (unchanged from R9): 8 uniform waves; LDS ring; exp2 nonlin ----------------
__launch_bounds__(512, 2)
__global__ void lstm_kernel(const float* __restrict__ gps0, const float* __restrict__ gps1, const float* __restrict__ gps2,
                            const int* __restrict__ grid0, const int* __restrict__ grid1, const int* __restrict__ grid2,
                            const f16* __restrict__ xgT, const f16* __restrict__ Whh_p,
                            const float* __restrict__ Wg_o,
                            const int* __restrict__ order, const int* __restrict__ slen,
                            const int* __restrict__ ev_t, const int* __restrict__ ev_slot, const int* __restrict__ nev,
                            float* __restrict__ stash)
{
    __shared__ f16   A_s[2][4][SROWH];
    __shared__ f16   ring[16][3][512];
    __shared__ float gpr[16][3][2];
    __shared__ int   gring[16][4];
    __shared__ int   ev_t_s[3][NEV];
    __shared__ int   ev_sl_s[3][NEV];

    const int tid  = threadIdx.x;
    const int lane = tid & 63;
    const int wv   = tid >> 6;
    const int q    = lane >> 4;
    const int li   = lane & 15;
    const int u    = (wv << 4) + li;
    const int qc   = (q < 3) ? q : 2;
    const int bi   = blockIdx.x;

    const int s0 = order[bi], s1 = order[bi+256], s2 = order[bi+512];
    const int l0 = slen[s0], l1 = slen[s1], l2 = slen[s2];
    int maxlen = l0 > l1 ? l0 : l1; if (l2 > maxlen) maxlen = l2;

    const int e0=s0>>8, b0=s0&255, e1=s1>>8, b1=s1&255, e2=s2>>8, b2=s2&255;
    const int* g0p = ((e0==0)?grid0:(e0==1)?grid1:grid2) + (size_t)b0*TT;
    const int* g1p = ((e1==0)?grid0:(e1==1)?grid1:grid2) + (size_t)b1*TT;
    const int* g2p = ((e2==0)?grid0:(e2==1)?grid1:grid2) + (size_t)b2*TT;
    const float* q0p = ((e0==0)?gps0:(e0==1)?gps1:gps2) + (size_t)b0*(TT*2);
    const float* q1p = ((e1==0)?gps0:(e1==1)?gps1:gps2) + (size_t)b1*(TT*2);
    const float* q2p = ((e2==0)?gps0:(e2==1)?gps1:gps2) + (size_t)b2*(TT*2);

    for (int i = tid; i < 2*4*SROWH; i += 512) (&A_s[0][0][0])[i] = (f16)0.f;
    if (tid < 72){
        int m = tid / NEV, i = tid % NEV;
        int sm = (m==0) ? s0 : (m==1) ? s1 : s2;
        ev_t_s[m][i]  = ev_t[sm*NEV + i];
        ev_sl_s[m][i] = ev_slot[sm*NEV + i];
    }

    f16x8 wI[4], wF[4], wG[4], wO[4];
    {
        const int kg = q << 3;
        #pragma unroll
        for (int ks = 0; ks < 4; ++ks){
            const int koff = ks*32 + kg;
            wI[ks] = *reinterpret_cast<const f16x8*>(Whh_p + (size_t)(  0 + u) * 128 + koff);
            wF[ks] = *reinterpret_cast<const f16x8*>(Whh_p + (size_t)(128 + u) * 128 + koff);
            wG[ks] = *reinterpret_cast<const f16x8*>(Whh_p + (size_t)(256 + u) * 128 + koff);
            wO[ks] = *reinterpret_cast<const f16x8*>(Whh_p + (size_t)(384 + u) * 128 + koff);
        }
    }
    float wgx4[4], wgy4[4];
    {
        f32x4 w0 = *reinterpret_cast<const f32x4*>(Wg_o + (u << 3));
        f32x4 w1 = *reinterpret_cast<const f32x4*>(Wg_o + (u << 3) + 4);
        wgx4[0]=w0[0]; wgy4[0]=w0[1]; wgx4[1]=w0[2]; wgy4[1]=w0[3];
        wgx4[2]=w1[0]; wgy4[2]=w1[1]; wgx4[3]=w1[2]; wgy4[3]=w1[3];
    }

    float creg = 0.f, hreg = 0.f;
    int len_q = 0, nev_q = 0, evp = 0, next_t = 1<<30;
    if (q < 3){
        int sq = (q==0)?s0:(q==1)?s1:s2;
        len_q = (q==0)?l0:(q==1)?l1:l2;
        nev_q = nev[sq];
    }
    const float* sgps = ((lane>>4)==0) ? q0p : ((lane>>4)==1) ? q1p : q2p;
    const int*   sgrd = ((lane>>3)==0) ? g0p : ((lane>>3)==1) ? g1p : g2p;

    {
        int wa = g0p[wv], wb = g1p[wv], wc = g2p[wv];
        gload_lds16(xgT + (size_t)wa*512 + (lane<<3), &ring[wv][0][0]);
        gload_lds16(xgT + (size_t)wb*512 + (lane<<3), &ring[wv][1][0]);
        gload_lds16(xgT + (size_t)wc*512 + (lane<<3), &ring[wv][2][0]);
    }
    if (tid < 48){
        int sm = tid >> 4, i = tid & 15;
        gpr[i>>1][sm][i&1] = ((sm==0)?q0p:(sm==1)?q1p:q2p)[i];
    }
    if (tid < 24){
        int sm = tid >> 3, i = tid & 7;
        gring[8+i][sm] = ((sm==0)?g0p:(sm==1)?g1p:g2p)[8+i];
    }
    __syncthreads();
    if (q < 3 && nev_q > 0) next_t = ev_t_s[qc][0];

#define STEP(T, P, P1, K)                                                                   \
{                                                                                           \
    f16x8 av[4];                                                                            \
    {                                                                                       \
        const f16* Arow = &A_s[P][li >> 2][q << 3];                                         \
        av[0] = *reinterpret_cast<const f16x8*>(Arow);                                      \
        av[1] = *reinterpret_cast<const f16x8*>(Arow + 32);                                 \
        av[2] = *reinterpret_cast<const f16x8*>(Arow + 64);                                 \
        av[3] = *reinterpret_cast<const f16x8*>(Arow + 96);                                 \
    }                                                                                       \
    const f16x4 xv = *reinterpret_cast<const f16x4*>(&ring[K][qc][u << 2]);                 \
    const float2 gp = *reinterpret_cast<const float2*>(&gpr[K][qc][0]);                     \
    if (((K) & 7) == 0){                                                                    \
        const int tb = ((K) + 8) & 15;                                                      \
        const int tsl = tb + wv;                                                            \
        int wd0 = gring[tsl][0];                                                            \
        int wd1 = gring[tsl][1];                                                            \
        int wd2 = gring[tsl][2];                                                            \
        gload_lds16(xgT + (size_t)wd0*512 + (lane<<3), &ring[tsl][0][0]);                   \
        gload_lds16(xgT + (size_t)wd1*512 + (lane<<3), &ring[tsl][1][0]);                   \
        gload_lds16(xgT + (size_t)wd2*512 + (lane<<3), &ring[tsl][2][0]);                   \
        if (wv == 6 && lane < 48){                                                          \
            int i2 = lane & 15, sm = lane >> 4;                                             \
            int tp = (T) + 8 + (i2 >> 1); if (tp > TT-1) tp = TT-1;                         \
            gpr[tb + (i2 >> 1)][sm][i2 & 1] = sgps[(size_t)tp*2 + (i2 & 1)];                \
        }                                                                                   \
        if (wv == 7 && lane < 24){                                                          \
            int i2 = lane & 7, sm = lane >> 3;                                              \
            int tp = (T) + 16 + i2; if (tp > TT-1) tp = TT-1;                               \
            gring[((K) & 8) + i2][sm] = sgrd[tp];                                           \
        }                                                                                   \
    }                                                                                       \
    const f32x4 zz = {0.f,0.f,0.f,0.f};                                                     \
    f32x4 iA = MF(av[1], wI[1], MF(av[0], wI[0], zz));                                      \
    f32x4 iB = MF(av[3], wI[3], MF(av[2], wI[2], zz));                                      \
    f32x4 fA = MF(av[1], wF[1], MF(av[0], wF[0], zz));                                      \
    f32x4 fB = MF(av[3], wF[3], MF(av[2], wF[2], zz));                                      \
    f32x4 gA = MF(av[1], wG[1], MF(av[0], wG[0], zz));                                      \
    f32x4 gB = MF(av[3], wG[3], MF(av[2], wG[2], zz));                                      \
    f32x4 oA = MF(av[1], wO[1], MF(av[0], wO[0], zz));                                      \
    f32x4 oB = MF(av[3], wO[3], MF(av[2], wO[2], zz));                                      \
    if (q < 3){                                                                             \
        float bI = fmaf(gp.y, wgy4[0], fmaf(gp.x, wgx4[0], (float)xv[0]));                  \
        float bF = fmaf(gp.y, wgy4[1], fmaf(gp.x, wgx4[1], (float)xv[1]));                  \
        float bG = fmaf(gp.y, wgy4[2], fmaf(gp.x, wgx4[2], (float)xv[2]));                  \
        float bO = fmaf(gp.y, wgy4[3], fmaf(gp.x, wgx4[3], (float)xv[3]));                  \
        float yI = (iA[0] + iB[0]) + bI;                                                    \
        float yF = (fA[0] + fB[0]) + bF;                                                    \
        float yG = (gA[0] + gB[0]) + bG;                                                    \
        float yO = (oA[0] + oB[0]) + bO;                                                    \
        if ((T) < len_q){                                                                   \
            float si = rcp_f(1.f + exp2_f(yI));                                             \
            float sf = rcp_f(1.f + exp2_f(yF));                                             \
            float so = rcp_f(1.f + exp2_f(yO));                                             \
            float tg = fmaf(-2.f, rcp_f(1.f + exp2_f(yG)), 1.f);                            \
            creg = fmaf(sf, creg, si * tg);                                                 \
            float th = fmaf(-2.f, rcp_f(1.f + exp2_f(S_TANH * creg)), 1.f);                 \
            hreg = so * th;                                                                 \
            while ((T) == next_t){                                                          \
                stash[(size_t)ev_sl_s[qc][evp]*HH + u] = hreg;                              \
                ++evp;                                                                      \
                next_t = (evp < nev_q) ? ev_t_s[qc][evp] : (1<<30);                         \
            }                                                                               \
        }                                                                                   \
        A_s[P1][q][u] = (f16)hreg;                                                          \
    }                                                                                       \
    if (((K) & 7) == 7) asm volatile("s_waitcnt vmcnt(0)" ::: "memory");                    \
    asm volatile("s_waitcnt lgkmcnt(0)" ::: "memory");                                      \
    __builtin_amdgcn_s_barrier();                                                           \
    asm volatile("" ::: "memory");                                                          \
}

    for (int t = 0; t < maxlen; t += 16){
        STEP(t+0,  0,1, 0)  STEP(t+1,  1,0, 1)  STEP(t+2,  0,1, 2)  STEP(t+3,  1,0, 3)
        STEP(t+4,  0,1, 4)  STEP(t+5,  1,0, 5)  STEP(t+6,  0,1, 6)  STEP(t+7,  1,0, 7)
        STEP(t+8,  0,1, 8)  STEP(t+9,  1,0, 9)  STEP(t+10, 0,1,10)  STEP(t+11, 1,0,11)
        STEP(t+12, 0,1,12)  STEP(t+13, 1,0,13)  STEP(t+14, 0,1,14)  STEP(t+15, 1,0,15)
    }
#undef STEP
}

// ---------------- fsim via MFMA: 64 rows/block, 3 GEMMs [64x128]@[128x128] + nonlin, in-place ----------------
#define FROWA 144
#define FROWF 132
__launch_bounds__(256)
__global__ void fsim_kernel(float* __restrict__ stash, const f16* __restrict__ Wfs,
                            const float* __restrict__ bi, const float* __restrict__ bc, const float* __restrict__ bo,
                            const int* __restrict__ sub_ta, const int* __restrict__ sub_tf,
                            const int* __restrict__ sub_a, const int* __restrict__ sub_f,
                            const int* __restrict__ len_t, const int* __restrict__ len_a, const int* __restrict__ len_f)
{
    __shared__ f16   hA[64][FROWA];
    __shared__ float hF[64][FROWF];
    __shared__ float bia[3][128];

    const int tid  = threadIdx.x;
    const int lane = tid & 63;
    const int wv   = tid >> 6;
    const int q    = lane >> 4;
    const int li   = lane & 15;
    const int base = blockIdx.x * 64;

    // stage h (masked) into f16 A-tile + f32 residual tile; thread -> (row, 32-col group)
    {
        const int row = tid >> 2, cg = tid & 3;
        const int grow = base + row;
        bool valid = true;
        if (grow < 10240){
            int g = grow / 2560, rr = grow % 2560, b = rr / 10;
            int sub, len;
            if (g == 0){ sub = sub_ta[rr]; len = len_t[b]; }
            else if (g == 1){ sub = sub_tf[rr]; len = len_t[b]; }
            else if (g == 2){ sub = sub_a[rr]; len = len_a[b]; }
            else { sub = sub_f[rr]; len = len_f[b]; }
            valid = (sub - 1) < len;
        }
        const f32x4* src = (const f32x4*)(stash + (size_t)grow*HH + cg*32);
        #pragma unroll
        for (int j2 = 0; j2 < 4; ++j2){
            f32x4 z = {0.f,0.f,0.f,0.f};
            f32x4 a = valid ? src[j2*2]     : z;
            f32x4 b = valid ? src[j2*2 + 1] : z;
            f16x8 t;
            t[0]=(f16)a[0]; t[1]=(f16)a[1]; t[2]=(f16)a[2]; t[3]=(f16)a[3];
            t[4]=(f16)b[0]; t[5]=(f16)b[1]; t[6]=(f16)b[2]; t[7]=(f16)b[3];
            *reinterpret_cast<f16x8*>(&hA[row][cg*32 + j2*8]) = t;
            *reinterpret_cast<f32x4*>(&hF[row][cg*32 + j2*8])     = a;
            *reinterpret_cast<f32x4*>(&hF[row][cg*32 + j2*8 + 4]) = b;
        }
    }
    if (tid < 384){
        int w = tid >> 7, uu = tid & 127;
        bia[w][uu] = ((w==0) ? bi : (w==1) ? bc : bo)[uu];
    }
    __syncthreads();

    // A-frags: wave wv owns rows [wv*16, wv*16+16)
    f16x8 av[4];
    {
        const f16* Arow = &hA[wv*16 + li][q << 3];
        #pragma unroll
        for (int ks = 0; ks < 4; ++ks)
            av[ks] = *reinterpret_cast<const f16x8*>(Arow + ks*32);
    }

    #pragma unroll
    for (int ct = 0; ct < 8; ++ct){
        const int col = ct*16 + li;
        f32x4 aI = {0.f,0.f,0.f,0.f}, aC = aI, aO = aI;
        #pragma unroll
        for (int ks = 0; ks < 4; ++ks){
            f16x8 bI8 = *reinterpret_cast<const f16x8*>(Wfs +           (size_t)col*128 + ks*32 + (q<<3));
            f16x8 bC8 = *reinterpret_cast<const f16x8*>(Wfs + 16384 +   (size_t)col*128 + ks*32 + (q<<3));
            f16x8 bO8 = *reinterpret_cast<const f16x8*>(Wfs + 32768 +   (size_t)col*128 + ks*32 + (q<<3));
            aI = MF(av[ks], bI8, aI);
            aC = MF(av[ks], bC8, aC);
            aO = MF(av[ks], bO8, aO);
        }
        const float BI = bia[0][col], BC = bia[1][col], BO = bia[2][col];
        #pragma unroll
        for (int reg = 0; reg < 4; ++reg){
            const int lrow = wv*16 + q*4 + reg;
            float C   = sigm_e(aI[reg] + BI) * tanh_e(aC[reg] + BC);
            float out = sigm_e(aO[reg] + BO) * tanh_e(C) + hF[lrow][col];
            stash[(size_t)(base + lrow)*HH + col] = out;
        }
    }
}

// ---------------- distances: out = exp(-||u - v||) ----------------
__global__ void dist_kernel(const float* __restrict__ fs, float* __restrict__ out)
{
    int gid = blockIdx.x * 256 + threadIdx.x;
    int pair = gid >> 6, ln = gid & 63;
    if (pair >= 5632) return;
    int ia, ib;
    if (pair < 256){ ia = 10240 + pair; ib = 10240 + 256 + pair; }
    else if (pair < 512){ int j = pair - 256; ia = 10240 + j; ib = 10240 + 512 + j; }
    else if (pair < 3072){ int j = pair - 512; ia = j; ib = 5120 + j; }
    else { int j = pair - 3072; ia = 2560 + j; ib = 7680 + j; }
    float d = 0.f;
    #pragma unroll
    for (int k = 0; k < 2; ++k){
        int kk = ln + k*64;
        float df = fs[(size_t)ia*HH + kk] - fs[(size_t)ib*HH + kk];
        d = fmaf(df, df, d);
    }
    #pragma unroll
    for (int off = 32; off > 0; off >>= 1) d += __shfl_xor(d, off);
    if (ln == 0) out[pair] = __expf(-sqrtf(d));
}

extern "C" void kernel_launch(void* const* d_in, const int* in_sizes, int n_in,
                              void* d_out, int out_size, void* d_ws, size_t ws_size,
                              hipStream_t stream)
{
    (void)n_in; (void)out_size; (void)ws_size;
    const float* traj_gps = (const float*)d_in[0];
    const int*   traj_grid = (const int*)d_in[2];
    const int*   traj_len = (const int*)d_in[4];
    const int*   sub_ta = (const int*)d_in[5];
    const int*   sub_tf = (const int*)d_in[6];
    const float* anc_gps = (const float*)d_in[7];
    const int*   anc_grid = (const int*)d_in[9];
    const int*   anc_len = (const int*)d_in[11];
    const int*   sub_a = (const int*)d_in[12];
    const float* far_gps = (const float*)d_in[13];
    const int*   far_grid = (const int*)d_in[15];
    const int*   far_len = (const int*)d_in[17];
    const int*   sub_f = (const int*)d_in[18];
    const float* E    = (const float*)d_in[19];
    const float* W_ih = (const float*)d_in[20];
    const float* W_hh = (const float*)d_in[21];
    const float* b_ih = (const float*)d_in[22];
    const float* b_hh = (const float*)d_in[23];
    const float* Wi = (const float*)d_in[24];
    const float* bi = (const float*)d_in[25];
    const float* Wc = (const float*)d_in[26];
    const float* bc = (const float*)d_in[27];
    const float* Wo = (const float*)d_in[28];
    const float* bo = (const float*)d_in[29];

    const int NW_rt = in_sizes[19] / HH;   // 50000

    char* p = (char*)d_ws;
    f16* Whh_p    = (f16*)p;   p += (size_t)512*128*2;
    f16* Wih_p    = (f16*)p;   p += (size_t)512*128*2;
    float* Wg_o   = (float*)p; p += 1024*4;
    float* bsum_o = (float*)p; p += 512*4;
    f16* Wfs      = (f16*)p;   p += (size_t)3*128*128*2;
    int* order    = (int*)p;   p += 768*4;
    int* slen     = (int*)p;   p += 768*4;
    int* ev_t     = (int*)p;   p += 768*NEV*4;
    int* ev_slot  = (int*)p;   p += 768*NEV*4;
    int* nev      = (int*)p;   p += 768*4;
    float* stash  = (float*)p; p += (size_t)11008*128*4;
    f16* xgT      = (f16*)p;   p += (size_t)NW_rt*512*2;

    pack_kernel<<<576, 256, 0, stream>>>(W_ih, W_hh, b_ih, b_hh, Wi, Wc, Wo,
                                         Whh_p, Wih_p, Wg_o, bsum_o, Wfs);
    xg_gemm<<<(NW_rt + 127)/128, 512, 0, stream>>>(E, Wih_p, bsum_o, xgT, NW_rt);
    sched_kernel<<<1, 768, 0, stream>>>(traj_len, anc_len, far_len, sub_ta, sub_tf, sub_a, sub_f,
                                        order, slen, ev_t, ev_slot, nev);
    lstm_kernel<<<256, 512, 0, stream>>>(traj_gps, anc_gps, far_gps, traj_grid, anc_grid, far_grid,
                                         xgT, Whh_p, Wg_o, order, slen, ev_t, ev_slot, nev, stash);
    fsim_kernel<<<172, 256, 0, stream>>>(stash, Wfs, bi, bc, bo, sub_ta, sub_tf, sub_a, sub_f,
                                         traj_len, anc_len, far_len);
    dist_kernel<<<1408, 256, 0, stream>>>(stash, (float*)d_out);
}

// Round 11
// 584.034 us; speedup vs baseline: 2.6193x; 1.1279x over previous
//
#include <hip/hip_runtime.h>
#include <math.h>

typedef _Float16 f16;
typedef _Float16 f16x8 __attribute__((ext_vector_type(8)));
typedef _Float16 f16x4 __attribute__((ext_vector_type(4)));
typedef float f32x4 __attribute__((ext_vector_type(4)));
typedef int i32x4 __attribute__((ext_vector_type(4)));

#define TT 1024
#define HH 128
#define SROWA 160    // bytes per A_s stream row (i8): 40 dwords -> 8-bank shift/row, 2-way max (free)
#define NEV 24

#define S_SIG  (-1.4426950408889634f)
#define S_TANH (2.8853900817779268f)

__device__ __forceinline__ float rcp_f(float x){ return __builtin_amdgcn_rcpf(x); }
__device__ __forceinline__ float exp2_f(float x){ return __builtin_amdgcn_exp2f(x); }
__device__ __forceinline__ float sigm_e(float x){ return rcp_f(1.f + exp2_f(S_SIG * x)); }
__device__ __forceinline__ float tanh_e(float x){ return fmaf(-2.f, rcp_f(1.f + exp2_f(S_TANH * x)), 1.f); }

#define MF(a,b,c)   __builtin_amdgcn_mfma_f32_16x16x32_f16((a),(b),(c),0,0,0)
#define MFI8(a,b,c) __builtin_amdgcn_mfma_i32_16x16x64_i8((a),(b),(c),0,0,0)

__device__ __forceinline__ void gload_lds16(const void* g, void* l){
    __builtin_amdgcn_global_load_lds((const __attribute__((address_space(1))) void*)g,
                                     (__attribute__((address_space(3))) void*)l, 16, 0, 0);
}

// ---------------- prep ----------------
// Whh_q: i8 W_hh rows j = g*128+u (per-row symmetric quant); dq_o[u*4+g] = s_row*scl[g]/127
// Wih_p: xg_gemm tiling rows j = nt*16+li_w hold W_ih row (g*128+u), p = li_w*32+nt = u*4+g
// Wg_o[p][c] scaled; bsum_o[p] unscaled (consumed+scaled in xg_gemm); Wfs = f16 Wi/Wc/Wo
__global__ void pack_kernel(const float* __restrict__ W_ih, const float* __restrict__ W_hh,
                            const float* __restrict__ b_ih, const float* __restrict__ b_hh,
                            const float* __restrict__ Wi, const float* __restrict__ Wc, const float* __restrict__ Wo,
                            signed char* __restrict__ Whh_q, float* __restrict__ dq_o, f16* __restrict__ Wih_p,
                            float* __restrict__ Wg_o, float* __restrict__ bsum_o, f16* __restrict__ Wfs)
{
    const float scl[4] = {S_SIG, S_SIG, S_TANH, S_SIG};
    int idx = blockIdx.x*256 + threadIdx.x;
    if (idx < 512*128){
        int j = idx >> 7, k = idx & 127;
        int p = ((j & 15) << 5) + (j >> 4);   // li_w*32 + nt
        int u = p >> 2, g = p & 3;
        Wih_p[idx] = (f16)W_ih[(g*128 + u)*130 + k];
    }
    if (idx < 512){
        // quantize one W_hh row
        int j = idx;
        float mx = 0.f;
        for (int k = 0; k < 128; ++k) mx = fmaxf(mx, fabsf(W_hh[j*128 + k]));
        float s = (mx > 0.f) ? mx * (1.f/127.f) : 1.f;
        float inv = 1.f / s;
        for (int k = 0; k < 128; ++k)
            Whh_q[j*128 + k] = (signed char)(int)rintf(W_hh[j*128 + k] * inv);
        int u = j & 127, g = j >> 7;
        dq_o[u*4 + g] = s * (1.f/127.f) * scl[g];
    }
    if (idx < 1024){
        int p = idx >> 1, c = idx & 1;
        int u = p >> 2, g = p & 3;
        Wg_o[idx] = W_ih[(g*128 + u)*130 + 128 + c] * scl[g];
    }
    if (idx >= 1024 && idx < 1536){
        int p = idx - 1024;
        int u = p >> 2, g = p & 3;
        bsum_o[p] = b_ih[g*128 + u] + b_hh[g*128 + u];
    }
    if (idx < 3*128*128){
        int w = idx >> 14, rem = idx & 16383;
        const float* W = (w==0) ? Wi : (w==1) ? Wc : Wo;
        Wfs[idx] = (f16)W[rem];
    }
}

// ---------------- precompute xgT[word][p] = scl[g]*(E0[word].W_ih^T + bias), f16, p-order ----------------
__global__ void xg_gemm(const float* __restrict__ E, const f16* __restrict__ Wih_p,
                        const float* __restrict__ bsum_o, f16* __restrict__ xgT, int NW)
{
    const float scl[4] = {S_SIG, S_SIG, S_TANH, S_SIG};
    const int w = threadIdx.x >> 6, lane = threadIdx.x & 63;
    const int li = lane & 15, q = lane >> 4;
    const int word = blockIdx.x*128 + w*16 + li;

    f16x8 a[4];
    const bool valid = (word > 0) && (word < NW);
    #pragma unroll
    for (int ks = 0; ks < 4; ++ks){
        f32x4 v0 = {0.f,0.f,0.f,0.f}, v1 = v0;
        if (valid){
            const f32x4* Er = (const f32x4*)(E + (size_t)word*HH);
            v0 = Er[ks*8 + q*2];
            v1 = Er[ks*8 + q*2 + 1];
        }
        f16x8 t;
        t[0]=(f16)v0[0]; t[1]=(f16)v0[1]; t[2]=(f16)v0[2]; t[3]=(f16)v0[3];
        t[4]=(f16)v1[0]; t[5]=(f16)v1[1]; t[6]=(f16)v1[2]; t[7]=(f16)v1[3];
        a[ks] = t;
    }
    const int wbase = blockIdx.x*128 + w*16 + q*4;
    #pragma unroll
    for (int grp = 0; grp < 4; ++grp){
        f32x4 acc_t[8];
        #pragma unroll
        for (int j8 = 0; j8 < 8; ++j8){
            const int nt = grp*8 + j8;
            f32x4 acc = {0.f,0.f,0.f,0.f};
            #pragma unroll
            for (int ks = 0; ks < 4; ++ks){
                f16x8 b = *reinterpret_cast<const f16x8*>(Wih_p + (size_t)(nt*16 + li)*128 + ks*32 + q*8);
                acc = MF(a[ks], b, acc);
            }
            acc_t[j8] = acc;
        }
        f32x4 bb0 = *reinterpret_cast<const f32x4*>(bsum_o + li*32 + grp*8);
        f32x4 bb1 = *reinterpret_cast<const f32x4*>(bsum_o + li*32 + grp*8 + 4);
        #pragma unroll
        for (int r = 0; r < 4; ++r){
            int wr = wbase + r;
            if (wr < NW){
                f16x8 v;
                #pragma unroll
                for (int j8 = 0; j8 < 8; ++j8){
                    float bias = (j8 < 4) ? bb0[j8] : bb1[j8-4];
                    v[j8] = (f16)((acc_t[j8][r] + bias) * scl[j8 & 3]);
                }
                *reinterpret_cast<f16x8*>(xgT + (size_t)wr*512 + li*32 + grp*8) = v;
            }
        }
    }
}

// ---------------- prep: length sort + per-stream event rank-sort (no scratch, fully unrolled) ----------------
__global__ void sched_kernel(const int* __restrict__ len_t, const int* __restrict__ len_a, const int* __restrict__ len_f,
                             const int* __restrict__ sub_ta, const int* __restrict__ sub_tf,
                             const int* __restrict__ sub_a, const int* __restrict__ sub_f,
                             int* __restrict__ order, int* __restrict__ slen,
                             int* __restrict__ ev_t, int* __restrict__ ev_slot, int* __restrict__ nev)
{
    __shared__ int L[768];
    int s = threadIdx.x;              // 0..767, stream id = e*256 + b
    int e = s >> 8, b = s & 255;
    int len = (e==0) ? len_t[b] : (e==1) ? len_a[b] : len_f[b];
    L[s] = len;
    __syncthreads();
    int rank = 0;
    for (int i = 0; i < 768; ++i){
        int li = L[i];
        rank += (li > len) || (li == len && i < s);
    }
    order[rank] = s;                  // descending by length, bijective
    slen[s] = len;

    int tv[21], sl[21];
    #pragma unroll
    for (int i = 0; i < 21; ++i){ tv[i] = -1; sl[i] = 0; }
    if (e == 0){
        #pragma unroll
        for (int r = 0; r < 10; ++r){
            tv[r]    = sub_ta[b*10+r] - 1;  sl[r]    = b*10 + r;
            tv[10+r] = sub_tf[b*10+r] - 1;  sl[10+r] = 2560 + b*10 + r;
        }
    } else if (e == 1){
        #pragma unroll
        for (int r = 0; r < 10; ++r){ tv[r] = sub_a[b*10+r] - 1; sl[r] = 5120 + b*10 + r; }
    } else {
        #pragma unroll
        for (int r = 0; r < 10; ++r){ tv[r] = sub_f[b*10+r] - 1; sl[r] = 7680 + b*10 + r; }
    }
    tv[20] = len - 1; sl[20] = 10240 + s;

    int n = 0;
    #pragma unroll
    for (int i = 0; i < 21; ++i){
        bool vi = (tv[i] >= 0) && (tv[i] < len);
        if (vi){
            int rk = 0;
            #pragma unroll
            for (int j = 0; j < 21; ++j){
                bool vj = (tv[j] >= 0) && (tv[j] < len);
                rk += (vj && ((tv[j] < tv[i]) || (tv[j] == tv[i] && j < i))) ? 1 : 0;
            }
            ev_t[s*NEV + rk]    = tv[i];
            ev_slot[s*NEV + rk] = sl[i];
            ++n;
        }
    }
    nev[s] = n;
}

// ---------------- main LSTM: 8 uniform waves; i8 K=64 MFMA (half the matrix work); LDS ring; exp2 nonlin ----------------
__launch_bounds__(512, 2)
__global__ void lstm_kernel(const float* __restrict__ gps0, const float* __restrict__ gps1, const float* __restrict__ gps2,
                            const int* __restrict__ grid0, const int* __restrict__ grid1, const int* __restrict__ grid2,
                            const f16* __restrict__ xgT, const signed char* __restrict__ Whh_q,
                            const float* __restrict__ dq_o, const float* __restrict__ Wg_o,
                            const int* __restrict__ order, const int* __restrict__ slen,
                            const int* __restrict__ ev_t, const int* __restrict__ ev_slot, const int* __restrict__ nev,
                            float* __restrict__ stash)
{
    __shared__ signed char A_s[2][4][SROWA];   // h quantized i8; rows 0..2 = streams, row 3 zero; dbuf
    __shared__ f16   ring[16][3][512];
    __shared__ float gpr[16][3][2];
    __shared__ int   gring[16][4];
    __shared__ int   ev_t_s[3][NEV];
    __shared__ int   ev_sl_s[3][NEV];

    const int tid  = threadIdx.x;
    const int lane = tid & 63;
    const int wv   = tid >> 6;
    const int q    = lane >> 4;
    const int li   = lane & 15;
    const int u    = (wv << 4) + li;
    const int qc   = (q < 3) ? q : 2;
    const int bi   = blockIdx.x;

    const int s0 = order[bi], s1 = order[bi+256], s2 = order[bi+512];
    const int l0 = slen[s0], l1 = slen[s1], l2 = slen[s2];
    int maxlen = l0 > l1 ? l0 : l1; if (l2 > maxlen) maxlen = l2;

    const int e0=s0>>8, b0=s0&255, e1=s1>>8, b1=s1&255, e2=s2>>8, b2=s2&255;
    const int* g0p = ((e0==0)?grid0:(e0==1)?grid1:grid2) + (size_t)b0*TT;
    const int* g1p = ((e1==0)?grid0:(e1==1)?grid1:grid2) + (size_t)b1*TT;
    const int* g2p = ((e2==0)?grid0:(e2==1)?grid1:grid2) + (size_t)b2*TT;
    const float* q0p = ((e0==0)?gps0:(e0==1)?gps1:gps2) + (size_t)b0*(TT*2);
    const float* q1p = ((e1==0)?gps0:(e1==1)?gps1:gps2) + (size_t)b1*(TT*2);
    const float* q2p = ((e2==0)?gps0:(e2==1)?gps1:gps2) + (size_t)b2*(TT*2);

    for (int i = tid; i < 2*4*SROWA; i += 512) (&A_s[0][0][0])[i] = 0;
    if (tid < 72){
        int m = tid / NEV, i = tid % NEV;
        int sm = (m==0) ? s0 : (m==1) ? s1 : s2;
        ev_t_s[m][i]  = ev_t[sm*NEV + i];
        ev_sl_s[m][i] = ev_slot[sm*NEV + i];
    }

    // ---- resident i8 weight fragments: 2 K-frags x 4 gates (32 VGPR) ----
    i32x4 wI8[2], wF8[2], wG8[2], wO8[2];
    {
        #pragma unroll
        for (int ks = 0; ks < 2; ++ks){
            const int off = ks*64 + (q << 4);
            wI8[ks] = *reinterpret_cast<const i32x4*>(Whh_q + (size_t)(  0 + u)*128 + off);
            wF8[ks] = *reinterpret_cast<const i32x4*>(Whh_q + (size_t)(128 + u)*128 + off);
            wG8[ks] = *reinterpret_cast<const i32x4*>(Whh_q + (size_t)(256 + u)*128 + off);
            wO8[ks] = *reinterpret_cast<const i32x4*>(Whh_q + (size_t)(384 + u)*128 + off);
        }
    }
    const f32x4 dq4 = *reinterpret_cast<const f32x4*>(dq_o + (u << 2));
    float wgx4[4], wgy4[4];
    {
        f32x4 w0 = *reinterpret_cast<const f32x4*>(Wg_o + (u << 3));
        f32x4 w1 = *reinterpret_cast<const f32x4*>(Wg_o + (u << 3) + 4);
        wgx4[0]=w0[0]; wgy4[0]=w0[1]; wgx4[1]=w0[2]; wgy4[1]=w0[3];
        wgx4[2]=w1[0]; wgy4[2]=w1[1]; wgx4[3]=w1[2]; wgy4[3]=w1[3];
    }

    float creg = 0.f, hreg = 0.f;
    int len_q = 0, nev_q = 0, evp = 0, next_t = 1<<30;
    if (q < 3){
        int sq = (q==0)?s0:(q==1)?s1:s2;
        len_q = (q==0)?l0:(q==1)?l1:l2;
        nev_q = nev[sq];
    }
    const float* sgps = ((lane>>4)==0) ? q0p : ((lane>>4)==1) ? q1p : q2p;
    const int*   sgrd = ((lane>>3)==0) ? g0p : ((lane>>3)==1) ? g1p : g2p;

    {
        int wa = g0p[wv], wb = g1p[wv], wc = g2p[wv];
        gload_lds16(xgT + (size_t)wa*512 + (lane<<3), &ring[wv][0][0]);
        gload_lds16(xgT + (size_t)wb*512 + (lane<<3), &ring[wv][1][0]);
        gload_lds16(xgT + (size_t)wc*512 + (lane<<3), &ring[wv][2][0]);
    }
    if (tid < 48){
        int sm = tid >> 4, i = tid & 15;
        gpr[i>>1][sm][i&1] = ((sm==0)?q0p:(sm==1)?q1p:q2p)[i];
    }
    if (tid < 24){
        int sm = tid >> 3, i = tid & 7;
        gring[8+i][sm] = ((sm==0)?g0p:(sm==1)?g1p:g2p)[8+i];
    }
    __syncthreads();
    if (q < 3 && nev_q > 0) next_t = ev_t_s[qc][0];

#define STEP(T, P, P1, K)                                                                   \
{                                                                                           \
    i32x4 av0, av1;                                                                         \
    {                                                                                       \
        const signed char* Ar = &A_s[P][li >> 2][q << 4];                                   \
        av0 = *reinterpret_cast<const i32x4*>(Ar);                                          \
        av1 = *reinterpret_cast<const i32x4*>(Ar + 64);                                     \
    }                                                                                       \
    const f16x4 xv = *reinterpret_cast<const f16x4*>(&ring[K][qc][u << 2]);                 \
    const float2 gp = *reinterpret_cast<const float2*>(&gpr[K][qc][0]);                     \
    if (((K) & 7) == 0){                                                                    \
        const int tb = ((K) + 8) & 15;                                                      \
        const int tsl = tb + wv;                                                            \
        int wd0 = gring[tsl][0];                                                            \
        int wd1 = gring[tsl][1];                                                            \
        int wd2 = gring[tsl][2];                                                            \
        gload_lds16(xgT + (size_t)wd0*512 + (lane<<3), &ring[tsl][0][0]);                   \
        gload_lds16(xgT + (size_t)wd1*512 + (lane<<3), &ring[tsl][1][0]);                   \
        gload_lds16(xgT + (size_t)wd2*512 + (lane<<3), &ring[tsl][2][0]);                   \
        if (wv == 6 && lane < 48){                                                          \
            int i2 = lane & 15, sm = lane >> 4;                                             \
            int tp = (T) + 8 + (i2 >> 1); if (tp > TT-1) tp = TT-1;                         \
            gpr[tb + (i2 >> 1)][sm][i2 & 1] = sgps[(size_t)tp*2 + (i2 & 1)];                \
        }                                                                                   \
        if (wv == 7 && lane < 24){                                                          \
            int i2 = lane & 7, sm = lane >> 3;                                              \
            int tp = (T) + 16 + i2; if (tp > TT-1) tp = TT-1;                               \
            gring[((K) & 8) + i2][sm] = sgrd[tp];                                           \
        }                                                                                   \
    }                                                                                       \
    const i32x4 z4 = {0,0,0,0};                                                             \
    i32x4 aI = MFI8(av1, wI8[1], MFI8(av0, wI8[0], z4));                                    \
    i32x4 aF = MFI8(av1, wF8[1], MFI8(av0, wF8[0], z4));                                    \
    i32x4 aG = MFI8(av1, wG8[1], MFI8(av0, wG8[0], z4));                                    \
    i32x4 aO = MFI8(av1, wO8[1], MFI8(av0, wO8[0], z4));                                    \
    if (q < 3){                                                                             \
        float bI = fmaf(gp.y, wgy4[0], fmaf(gp.x, wgx4[0], (float)xv[0]));                  \
        float bF = fmaf(gp.y, wgy4[1], fmaf(gp.x, wgx4[1], (float)xv[1]));                  \
        float bG = fmaf(gp.y, wgy4[2], fmaf(gp.x, wgx4[2], (float)xv[2]));                  \
        float bO = fmaf(gp.y, wgy4[3], fmaf(gp.x, wgx4[3], (float)xv[3]));                  \
        float yI = fmaf((float)aI[0], dq4[0], bI);                                          \
        float yF = fmaf((float)aF[0], dq4[1], bF);                                          \
        float yG = fmaf((float)aG[0], dq4[2], bG);                                          \
        float yO = fmaf((float)aO[0], dq4[3], bO);                                          \
        if ((T) < len_q){                                                                   \
            float si = rcp_f(1.f + exp2_f(yI));                                             \
            float sf = rcp_f(1.f + exp2_f(yF));                                             \
            float so = rcp_f(1.f + exp2_f(yO));                                             \
            float tg = fmaf(-2.f, rcp_f(1.f + exp2_f(yG)), 1.f);                            \
            creg = fmaf(sf, creg, si * tg);                                                 \
            float th = fmaf(-2.f, rcp_f(1.f + exp2_f(S_TANH * creg)), 1.f);                 \
            hreg = so * th;                                                                 \
            while ((T) == next_t){                                                          \
                stash[(size_t)ev_sl_s[qc][evp]*HH + u] = hreg;                              \
                ++evp;                                                                      \
                next_t = (evp < nev_q) ? ev_t_s[qc][evp] : (1<<30);                         \
            }                                                                               \
        }                                                                                   \
        int hi8 = (int)rintf(hreg * 127.f);                                                 \
        A_s[P1][q][u] = (signed char)hi8;                                                   \
    }                                                                                       \
    if (((K) & 7) == 7) asm volatile("s_waitcnt vmcnt(0)" ::: "memory");                    \
    asm volatile("s_waitcnt lgkmcnt(0)" ::: "memory");                                      \
    __builtin_amdgcn_s_barrier();                                                           \
    asm volatile("" ::: "memory");                                                          \
}

    for (int t = 0; t < maxlen; t += 16){
        STEP(t+0,  0,1, 0)  STEP(t+1,  1,0, 1)  STEP(t+2,  0,1, 2)  STEP(t+3,  1,0, 3)
        STEP(t+4,  0,1, 4)  STEP(t+5,  1,0, 5)  STEP(t+6,  0,1, 6)  STEP(t+7,  1,0, 7)
        STEP(t+8,  0,1, 8)  STEP(t+9,  1,0, 9)  STEP(t+10, 0,1,10)  STEP(t+11, 1,0,11)
        STEP(t+12, 0,1,12)  STEP(t+13, 1,0,13)  STEP(t+14, 0,1,14)  STEP(t+15, 1,0,15)
    }
#undef STEP
}

// ---------------- fsim via MFMA: 64 rows/block, 3 GEMMs [64x128]@[128x128] + nonlin, in-place ----------------
#define FROWA 144
#define FROWF 132
__launch_bounds__(256)
__global__ void fsim_kernel(float* __restrict__ stash, const f16* __restrict__ Wfs,
                            const float* __restrict__ bi, const float* __restrict__ bc, const float* __restrict__ bo,
                            const int* __restrict__ sub_ta, const int* __restrict__ sub_tf,
                            const int* __restrict__ sub_a, const int* __restrict__ sub_f,
                            const int* __restrict__ len_t, const int* __restrict__ len_a, const int* __restrict__ len_f)
{
    __shared__ f16   hA[64][FROWA];
    __shared__ float hF[64][FROWF];
    __shared__ float bia[3][128];

    const int tid  = threadIdx.x;
    const int lane = tid & 63;
    const int wv   = tid >> 6;
    const int q    = lane >> 4;
    const int li   = lane & 15;
    const int base = blockIdx.x * 64;

    {
        const int row = tid >> 2, cg = tid & 3;
        const int grow = base + row;
        bool valid = true;
        if (grow < 10240){
            int g = grow / 2560, rr = grow % 2560, b = rr / 10;
            int sub, len;
            if (g == 0){ sub = sub_ta[rr]; len = len_t[b]; }
            else if (g == 1){ sub = sub_tf[rr]; len = len_t[b]; }
            else if (g == 2){ sub = sub_a[rr]; len = len_a[b]; }
            else { sub = sub_f[rr]; len = len_f[b]; }
            valid = (sub - 1) < len;
        }
        const f32x4* src = (const f32x4*)(stash + (size_t)grow*HH + cg*32);
        #pragma unroll
        for (int j2 = 0; j2 < 4; ++j2){
            f32x4 z = {0.f,0.f,0.f,0.f};
            f32x4 a = valid ? src[j2*2]     : z;
            f32x4 b = valid ? src[j2*2 + 1] : z;
            f16x8 t;
            t[0]=(f16)a[0]; t[1]=(f16)a[1]; t[2]=(f16)a[2]; t[3]=(f16)a[3];
            t[4]=(f16)b[0]; t[5]=(f16)b[1]; t[6]=(f16)b[2]; t[7]=(f16)b[3];
            *reinterpret_cast<f16x8*>(&hA[row][cg*32 + j2*8]) = t;
            *reinterpret_cast<f32x4*>(&hF[row][cg*32 + j2*8])     = a;
            *reinterpret_cast<f32x4*>(&hF[row][cg*32 + j2*8 + 4]) = b;
        }
    }
    if (tid < 384){
        int w = tid >> 7, uu = tid & 127;
        bia[w][uu] = ((w==0) ? bi : (w==1) ? bc : bo)[uu];
    }
    __syncthreads();

    f16x8 av[4];
    {
        const f16* Arow = &hA[wv*16 + li][q << 3];
        #pragma unroll
        for (int ks = 0; ks < 4; ++ks)
            av[ks] = *reinterpret_cast<const f16x8*>(Arow + ks*32);
    }

    #pragma unroll
    for (int ct = 0; ct < 8; ++ct){
        const int col = ct*16 + li;
        f32x4 aI = {0.f,0.f,0.f,0.f}, aC = aI, aO = aI;
        #pragma unroll
        for (int ks = 0; ks < 4; ++ks){
            f16x8 bI8 = *reinterpret_cast<const f16x8*>(Wfs +           (size_t)col*128 + ks*32 + (q<<3));
            f16x8 bC8 = *reinterpret_cast<const f16x8*>(Wfs + 16384 +   (size_t)col*128 + ks*32 + (q<<3));
            f16x8 bO8 = *reinterpret_cast<const f16x8*>(Wfs + 32768 +   (size_t)col*128 + ks*32 + (q<<3));
            aI = MF(av[ks], bI8, aI);
            aC = MF(av[ks], bC8, aC);
            aO = MF(av[ks], bO8, aO);
        }
        const float BI = bia[0][col], BC = bia[1][col], BO = bia[2][col];
        #pragma unroll
        for (int reg = 0; reg < 4; ++reg){
            const int lrow = wv*16 + q*4 + reg;
            float C   = sigm_e(aI[reg] + BI) * tanh_e(aC[reg] + BC);
            float out = sigm_e(aO[reg] + BO) * tanh_e(C) + hF[lrow][col];
            stash[(size_t)(base + lrow)*HH + col] = out;
        }
    }
}

// ---------------- distances: out = exp(-||u - v||) ----------------
__global__ void dist_kernel(const float* __restrict__ fs, float* __restrict__ out)
{
    int gid = blockIdx.x * 256 + threadIdx.x;
    int pair = gid >> 6, ln = gid & 63;
    if (pair >= 5632) return;
    int ia, ib;
    if (pair < 256){ ia = 10240 + pair; ib = 10240 + 256 + pair; }
    else if (pair < 512){ int j = pair - 256; ia = 10240 + j; ib = 10240 + 512 + j; }
    else if (pair < 3072){ int j = pair - 512; ia = j; ib = 5120 + j; }
    else { int j = pair - 3072; ia = 2560 + j; ib = 7680 + j; }
    float d = 0.f;
    #pragma unroll
    for (int k = 0; k < 2; ++k){
        int kk = ln + k*64;
        float df = fs[(size_t)ia*HH + kk] - fs[(size_t)ib*HH + kk];
        d = fmaf(df, df, d);
    }
    #pragma unroll
    for (int off = 32; off > 0; off >>= 1) d += __shfl_xor(d, off);
    if (ln == 0) out[pair] = __expf(-sqrtf(d));
}

extern "C" void kernel_launch(void* const* d_in, const int* in_sizes, int n_in,
                              void* d_out, int out_size, void* d_ws, size_t ws_size,
                              hipStream_t stream)
{
    (void)n_in; (void)out_size; (void)ws_size;
    const float* traj_gps = (const float*)d_in[0];
    const int*   traj_grid = (const int*)d_in[2];
    const int*   traj_len = (const int*)d_in[4];
    const int*   sub_ta = (const int*)d_in[5];
    const int*   sub_tf = (const int*)d_in[6];
    const float* anc_gps = (const float*)d_in[7];
    const int*   anc_grid = (const int*)d_in[9];
    const int*   anc_len = (const int*)d_in[11];
    const int*   sub_a = (const int*)d_in[12];
    const float* far_gps = (const float*)d_in[13];
    const int*   far_grid = (const int*)d_in[15];
    const int*   far_len = (const int*)d_in[17];
    const int*   sub_f = (const int*)d_in[18];
    const float* E    = (const float*)d_in[19];
    const float* W_ih = (const float*)d_in[20];
    const float* W_hh = (const float*)d_in[21];
    const float* b_ih = (const float*)d_in[22];
    const float* b_hh = (const float*)d_in[23];
    const float* Wi = (const float*)d_in[24];
    const float* bi = (const float*)d_in[25];
    const float* Wc = (const float*)d_in[26];
    const float* bc = (const float*)d_in[27];
    const float* Wo = (const float*)d_in[28];
    const float* bo = (const float*)d_in[29];

    const int NW_rt = in_sizes[19] / HH;   // 50000

    char* p = (char*)d_ws;
    signed char* Whh_q = (signed char*)p; p += (size_t)512*128;
    float* dq_o   = (float*)p; p += 512*4;
    f16* Wih_p    = (f16*)p;   p += (size_t)512*128*2;
    float* Wg_o   = (float*)p; p += 1024*4;
    float* bsum_o = (float*)p; p += 512*4;
    f16* Wfs      = (f16*)p;   p += (size_t)3*128*128*2;
    int* order    = (int*)p;   p += 768*4;
    int* slen     = (int*)p;   p += 768*4;
    int* ev_t     = (int*)p;   p += 768*NEV*4;
    int* ev_slot  = (int*)p;   p += 768*NEV*4;
    int* nev      = (int*)p;   p += 768*4;
    float* stash  = (float*)p; p += (size_t)11008*128*4;
    f16* xgT      = (f16*)p;   p += (size_t)NW_rt*512*2;

    pack_kernel<<<576, 256, 0, stream>>>(W_ih, W_hh, b_ih, b_hh, Wi, Wc, Wo,
                                         Whh_q, dq_o, Wih_p, Wg_o, bsum_o, Wfs);
    xg_gemm<<<(NW_rt + 127)/128, 512, 0, stream>>>(E, Wih_p, bsum_o, xgT, NW_rt);
    sched_kernel<<<1, 768, 0, stream>>>(traj_len, anc_len, far_len, sub_ta, sub_tf, sub_a, sub_f,
                                        order, slen, ev_t, ev_slot, nev);
    lstm_kernel<<<256, 512, 0, stream>>>(traj_gps, anc_gps, far_gps, traj_grid, anc_grid, far_grid,
                                         xgT, Whh_q, dq_o, Wg_o, order, slen, ev_t, ev_slot, nev, stash);
    fsim_kernel<<<172, 256, 0, stream>>>(stash, Wfs, bi, bc, bo, sub_ta, sub_tf, sub_a, sub_f,
                                         traj_len, anc_len, far_len);
    dist_kernel<<<1408, 256, 0, stream>>>(stash, (float*)d_out);
}

// Round 13
// 570.985 us; speedup vs baseline: 2.6791x; 1.0229x over previous
//
#include <hip/hip_runtime.h>
#include <math.h>

typedef _Float16 f16;
typedef _Float16 f16x8 __attribute__((ext_vector_type(8)));
typedef _Float16 f16x4 __attribute__((ext_vector_type(4)));
typedef float f32x4 __attribute__((ext_vector_type(4)));
typedef int i32x4 __attribute__((ext_vector_type(4)));

#define TT 1024
#define HH 128
#define SROWA 160    // bytes per A_s stream row (i8)
#define NEV 24

#define S_SIG  (-1.4426950408889634f)
#define S_TANH (2.8853900817779268f)

__device__ __forceinline__ float rcp_f(float x){ return __builtin_amdgcn_rcpf(x); }
__device__ __forceinline__ float exp2_f(float x){ return __builtin_amdgcn_exp2f(x); }
__device__ __forceinline__ float sigm_e(float x){ return rcp_f(1.f + exp2_f(S_SIG * x)); }
__device__ __forceinline__ float tanh_e(float x){ return fmaf(-2.f, rcp_f(1.f + exp2_f(S_TANH * x)), 1.f); }

#define MF(a,b,c)   __builtin_amdgcn_mfma_f32_16x16x32_f16((a),(b),(c),0,0,0)
#define MFI8(a,b,c) __builtin_amdgcn_mfma_i32_16x16x64_i8((a),(b),(c),0,0,0)

__device__ __forceinline__ void gload_lds16(const void* g, void* l){
    __builtin_amdgcn_global_load_lds((const __attribute__((address_space(1))) void*)g,
                                     (__attribute__((address_space(3))) void*)l, 16, 0, 0);
}

// ---------------- prep ----------------
// Whh_q: i8 W_hh rows j = g*128+u (per-row symmetric quant); dq_o[u*4+g] = s_row*scl[g]/127
// Wih_p: xg_gemm tiling rows j = nt*16+li_w hold W_ih row (g*128+u), p = li_w*32+nt = u*4+g
// Wg_o[p][c] scaled; bsum_o[p] unscaled (consumed+scaled in xg_gemm); Wfs = f16 Wi/Wc/Wo
__global__ void pack_kernel(const float* __restrict__ W_ih, const float* __restrict__ W_hh,
                            const float* __restrict__ b_ih, const float* __restrict__ b_hh,
                            const float* __restrict__ Wi, const float* __restrict__ Wc, const float* __restrict__ Wo,
                            signed char* __restrict__ Whh_q, float* __restrict__ dq_o, f16* __restrict__ Wih_p,
                            float* __restrict__ Wg_o, float* __restrict__ bsum_o, f16* __restrict__ Wfs)
{
    const float scl[4] = {S_SIG, S_SIG, S_TANH, S_SIG};
    int idx = blockIdx.x*256 + threadIdx.x;
    if (idx < 512*128){
        int j = idx >> 7, k = idx & 127;
        int p = ((j & 15) << 5) + (j >> 4);
        int u = p >> 2, g = p & 3;
        Wih_p[idx] = (f16)W_ih[(g*128 + u)*130 + k];
    }
    if (idx < 512){
        int j = idx;
        float mx = 0.f;
        for (int k = 0; k < 128; ++k) mx = fmaxf(mx, fabsf(W_hh[j*128 + k]));
        float s = (mx > 0.f) ? mx * (1.f/127.f) : 1.f;
        float inv = 1.f / s;
        for (int k = 0; k < 128; ++k)
            Whh_q[j*128 + k] = (signed char)(int)rintf(W_hh[j*128 + k] * inv);
        int u = j & 127, g = j >> 7;
        dq_o[u*4 + g] = s * (1.f/127.f) * scl[g];
    }
    if (idx < 1024){
        int p = idx >> 1, c = idx & 1;
        int u = p >> 2, g = p & 3;
        Wg_o[idx] = W_ih[(g*128 + u)*130 + 128 + c] * scl[g];
    }
    if (idx >= 1024 && idx < 1536){
        int p = idx - 1024;
        int u = p >> 2, g = p & 3;
        bsum_o[p] = b_ih[g*128 + u] + b_hh[g*128 + u];
    }
    if (idx < 3*128*128){
        int w = idx >> 14, rem = idx & 16383;
        const float* W = (w==0) ? Wi : (w==1) ? Wc : Wo;
        Wfs[idx] = (f16)W[rem];
    }
}

// ---------------- precompute xgT[word][p] = scl[g]*(E0[word].W_ih^T + bias), f16, p-order ----------------
__global__ void xg_gemm(const float* __restrict__ E, const f16* __restrict__ Wih_p,
                        const float* __restrict__ bsum_o, f16* __restrict__ xgT, int NW)
{
    const float scl[4] = {S_SIG, S_SIG, S_TANH, S_SIG};
    const int w = threadIdx.x >> 6, lane = threadIdx.x & 63;
    const int li = lane & 15, q = lane >> 4;
    const int word = blockIdx.x*128 + w*16 + li;

    f16x8 a[4];
    const bool valid = (word > 0) && (word < NW);
    #pragma unroll
    for (int ks = 0; ks < 4; ++ks){
        f32x4 v0 = {0.f,0.f,0.f,0.f}, v1 = v0;
        if (valid){
            const f32x4* Er = (const f32x4*)(E + (size_t)word*HH);
            v0 = Er[ks*8 + q*2];
            v1 = Er[ks*8 + q*2 + 1];
        }
        f16x8 t;
        t[0]=(f16)v0[0]; t[1]=(f16)v0[1]; t[2]=(f16)v0[2]; t[3]=(f16)v0[3];
        t[4]=(f16)v1[0]; t[5]=(f16)v1[1]; t[6]=(f16)v1[2]; t[7]=(f16)v1[3];
        a[ks] = t;
    }
    const int wbase = blockIdx.x*128 + w*16 + q*4;
    #pragma unroll
    for (int grp = 0; grp < 4; ++grp){
        f32x4 acc_t[8];
        #pragma unroll
        for (int j8 = 0; j8 < 8; ++j8){
            const int nt = grp*8 + j8;
            f32x4 acc = {0.f,0.f,0.f,0.f};
            #pragma unroll
            for (int ks = 0; ks < 4; ++ks){
                f16x8 b = *reinterpret_cast<const f16x8*>(Wih_p + (size_t)(nt*16 + li)*128 + ks*32 + q*8);
                acc = MF(a[ks], b, acc);
            }
            acc_t[j8] = acc;
        }
        f32x4 bb0 = *reinterpret_cast<const f32x4*>(bsum_o + li*32 + grp*8);
        f32x4 bb1 = *reinterpret_cast<const f32x4*>(bsum_o + li*32 + grp*8 + 4);
        #pragma unroll
        for (int r = 0; r < 4; ++r){
            int wr = wbase + r;
            if (wr < NW){
                f16x8 v;
                #pragma unroll
                for (int j8 = 0; j8 < 8; ++j8){
                    float bias = (j8 < 4) ? bb0[j8] : bb1[j8-4];
                    v[j8] = (f16)((acc_t[j8][r] + bias) * scl[j8 & 3]);
                }
                *reinterpret_cast<f16x8*>(xgT + (size_t)wr*512 + li*32 + grp*8) = v;
            }
        }
    }
}

// ---------------- prep: length sort + per-stream event rank-sort (no scratch, fully unrolled) ----------------
__global__ void sched_kernel(const int* __restrict__ len_t, const int* __restrict__ len_a, const int* __restrict__ len_f,
                             const int* __restrict__ sub_ta, const int* __restrict__ sub_tf,
                             const int* __restrict__ sub_a, const int* __restrict__ sub_f,
                             int* __restrict__ order, int* __restrict__ slen,
                             int* __restrict__ ev_t, int* __restrict__ ev_slot, int* __restrict__ nev)
{
    __shared__ int L[768];
    int s = threadIdx.x;              // 0..767, stream id = e*256 + b
    int e = s >> 8, b = s & 255;
    int len = (e==0) ? len_t[b] : (e==1) ? len_a[b] : len_f[b];
    L[s] = len;
    __syncthreads();
    int rank = 0;
    for (int i = 0; i < 768; ++i){
        int li = L[i];
        rank += (li > len) || (li == len && i < s);
    }
    order[rank] = s;                  // descending by length, bijective
    slen[s] = len;

    int tv[21], sl[21];
    #pragma unroll
    for (int i = 0; i < 21; ++i){ tv[i] = -1; sl[i] = 0; }
    if (e == 0){
        #pragma unroll
        for (int r = 0; r < 10; ++r){
            tv[r]    = sub_ta[b*10+r] - 1;  sl[r]    = b*10 + r;
            tv[10+r] = sub_tf[b*10+r] - 1;  sl[10+r] = 2560 + b*10 + r;
        }
    } else if (e == 1){
        #pragma unroll
        for (int r = 0; r < 10; ++r){ tv[r] = sub_a[b*10+r] - 1; sl[r] = 5120 + b*10 + r; }
    } else {
        #pragma unroll
        for (int r = 0; r < 10; ++r){ tv[r] = sub_f[b*10+r] - 1; sl[r] = 7680 + b*10 + r; }
    }
    tv[20] = len - 1; sl[20] = 10240 + s;

    int n = 0;
    #pragma unroll
    for (int i = 0; i < 21; ++i){
        bool vi = (tv[i] >= 0) && (tv[i] < len);
        if (vi){
            int rk = 0;
            #pragma unroll
            for (int j = 0; j < 21; ++j){
                bool vj = (tv[j] >= 0) && (tv[j] < len);
                rk += (vj && ((tv[j] < tv[i]) || (tv[j] == tv[i] && j < i))) ? 1 : 0;
            }
            ev_t[s*NEV + rk]    = tv[i];
            ev_slot[s*NEV + rk] = sl[i];
            ++n;
        }
    }
    nev[s] = n;
}

// ---------------- main LSTM: 8 uniform waves; i8 K=64 MFMA, 8 INDEPENDENT per step; LDS ring; exp2 nonlin ----------------
__launch_bounds__(512, 2)
__global__ void lstm_kernel(const float* __restrict__ gps0, const float* __restrict__ gps1, const float* __restrict__ gps2,
                            const int* __restrict__ grid0, const int* __restrict__ grid1, const int* __restrict__ grid2,
                            const f16* __restrict__ xgT, const signed char* __restrict__ Whh_q,
                            const float* __restrict__ dq_o, const float* __restrict__ Wg_o,
                            const int* __restrict__ order, const int* __restrict__ slen,
                            const int* __restrict__ ev_t, const int* __restrict__ ev_slot, const int* __restrict__ nev,
                            float* __restrict__ stash)
{
    __shared__ signed char A_s[2][4][SROWA];   // h quantized i8; rows 0..2 = streams, row 3 zero; dbuf
    __shared__ f16   ring[16][3][512];
    __shared__ float gpr[16][3][2];
    __shared__ int   gring[16][4];
    __shared__ int   ev_t_s[3][NEV];
    __shared__ int   ev_sl_s[3][NEV];

    const int tid  = threadIdx.x;
    const int lane = tid & 63;
    const int wv   = tid >> 6;
    const int q    = lane >> 4;
    const int li   = lane & 15;
    const int u    = (wv << 4) + li;
    const int qc   = (q < 3) ? q : 2;
    const int bi   = blockIdx.x;

    const int s0 = order[bi], s1 = order[bi+256], s2 = order[bi+512];
    const int l0 = slen[s0], l1 = slen[s1], l2 = slen[s2];
    int maxlen = l0 > l1 ? l0 : l1; if (l2 > maxlen) maxlen = l2;

    const int e0=s0>>8, b0=s0&255, e1=s1>>8, b1=s1&255, e2=s2>>8, b2=s2&255;
    const int* g0p = ((e0==0)?grid0:(e0==1)?grid1:grid2) + (size_t)b0*TT;
    const int* g1p = ((e1==0)?grid0:(e1==1)?grid1:grid2) + (size_t)b1*TT;
    const int* g2p = ((e2==0)?grid0:(e2==1)?grid1:grid2) + (size_t)b2*TT;
    const float* q0p = ((e0==0)?gps0:(e0==1)?gps1:gps2) + (size_t)b0*(TT*2);
    const float* q1p = ((e1==0)?gps0:(e1==1)?gps1:gps2) + (size_t)b1*(TT*2);
    const float* q2p = ((e2==0)?gps0:(e2==1)?gps1:gps2) + (size_t)b2*(TT*2);

    for (int i = tid; i < 2*4*SROWA; i += 512) (&A_s[0][0][0])[i] = 0;
    if (tid < 72){
        int m = tid / NEV, i = tid % NEV;
        int sm = (m==0) ? s0 : (m==1) ? s1 : s2;
        ev_t_s[m][i]  = ev_t[sm*NEV + i];
        ev_sl_s[m][i] = ev_slot[sm*NEV + i];
    }

    // ---- resident i8 weight fragments: 2 K-frags x 4 gates (32 VGPR) ----
    i32x4 wI8[2], wF8[2], wG8[2], wO8[2];
    {
        #pragma unroll
        for (int ks = 0; ks < 2; ++ks){
            const int off = ks*64 + (q << 4);
            wI8[ks] = *reinterpret_cast<const i32x4*>(Whh_q + (size_t)(  0 + u)*128 + off);
            wF8[ks] = *reinterpret_cast<const i32x4*>(Whh_q + (size_t)(128 + u)*128 + off);
            wG8[ks] = *reinterpret_cast<const i32x4*>(Whh_q + (size_t)(256 + u)*128 + off);
            wO8[ks] = *reinterpret_cast<const i32x4*>(Whh_q + (size_t)(384 + u)*128 + off);
        }
    }
    const f32x4 dq4 = *reinterpret_cast<const f32x4*>(dq_o + (u << 2));
    float wgx4[4], wgy4[4];
    {
        f32x4 w0 = *reinterpret_cast<const f32x4*>(Wg_o + (u << 3));
        f32x4 w1 = *reinterpret_cast<const f32x4*>(Wg_o + (u << 3) + 4);
        wgx4[0]=w0[0]; wgy4[0]=w0[1]; wgx4[1]=w0[2]; wgy4[1]=w0[3];
        wgx4[2]=w1[0]; wgy4[2]=w1[1]; wgx4[3]=w1[2]; wgy4[3]=w1[3];
    }

    float creg = 0.f, hreg = 0.f;
    int len_q = 0, nev_q = 0, evp = 0, next_t = 1<<30;
    if (q < 3){
        int sq = (q==0)?s0:(q==1)?s1:s2;
        len_q = (q==0)?l0:(q==1)?l1:l2;
        nev_q = nev[sq];
    }
    const float* sgps = ((lane>>4)==0) ? q0p : ((lane>>4)==1) ? q1p : q2p;
    const int*   sgrd = ((lane>>3)==0) ? g0p : ((lane>>3)==1) ? g1p : g2p;

    {
        int wa = g0p[wv], wb = g1p[wv], wc = g2p[wv];
        gload_lds16(xgT + (size_t)wa*512 + (lane<<3), &ring[wv][0][0]);
        gload_lds16(xgT + (size_t)wb*512 + (lane<<3), &ring[wv][1][0]);
        gload_lds16(xgT + (size_t)wc*512 + (lane<<3), &ring[wv][2][0]);
    }
    if (tid < 48){
        int sm = tid >> 4, i = tid & 15;
        gpr[i>>1][sm][i&1] = ((sm==0)?q0p:(sm==1)?q1p:q2p)[i];
    }
    if (tid < 24){
        int sm = tid >> 3, i = tid & 7;
        gring[8+i][sm] = ((sm==0)?g0p:(sm==1)?g1p:g2p)[8+i];
    }
    __syncthreads();
    if (q < 3 && nev_q > 0) next_t = ev_t_s[qc][0];

#define STEP(T, P, P1, K)                                                                   \
{                                                                                           \
    i32x4 av0, av1;                                                                         \
    {                                                                                       \
        const signed char* Ar = &A_s[P][li >> 2][q << 4];                                   \
        av0 = *reinterpret_cast<const i32x4*>(Ar);                                          \
        av1 = *reinterpret_cast<const i32x4*>(Ar + 64);                                     \
    }                                                                                       \
    const f16x4 xv = *reinterpret_cast<const f16x4*>(&ring[K][qc][u << 2]);                 \
    const float2 gp = *reinterpret_cast<const float2*>(&gpr[K][qc][0]);                     \
    if (((K) & 7) == 0){                                                                    \
        const int tb = ((K) + 8) & 15;                                                      \
        const int tsl = tb + wv;                                                            \
        int wd0 = gring[tsl][0];                                                            \
        int wd1 = gring[tsl][1];                                                            \
        int wd2 = gring[tsl][2];                                                            \
        gload_lds16(xgT + (size_t)wd0*512 + (lane<<3), &ring[tsl][0][0]);                   \
        gload_lds16(xgT + (size_t)wd1*512 + (lane<<3), &ring[tsl][1][0]);                   \
        gload_lds16(xgT + (size_t)wd2*512 + (lane<<3), &ring[tsl][2][0]);                   \
        if (wv == 6 && lane < 48){                                                          \
            int i2 = lane & 15, sm = lane >> 4;                                             \
            int tp = (T) + 8 + (i2 >> 1); if (tp > TT-1) tp = TT-1;                         \
            gpr[tb + (i2 >> 1)][sm][i2 & 1] = sgps[(size_t)tp*2 + (i2 & 1)];                \
        }                                                                                   \
        if (wv == 7 && lane < 24){                                                          \
            int i2 = lane & 7, sm = lane >> 3;                                              \
            int tp = (T) + 16 + i2; if (tp > TT-1) tp = TT-1;                               \
            gring[((K) & 8) + i2][sm] = sgrd[tp];                                           \
        }                                                                                   \
    }                                                                                       \
    const i32x4 z4 = {0,0,0,0};                                                             \
    i32x4 aI0 = MFI8(av0, wI8[0], z4);                                                      \
    i32x4 aF0 = MFI8(av0, wF8[0], z4);                                                      \
    i32x4 aG0 = MFI8(av0, wG8[0], z4);                                                      \
    i32x4 aO0 = MFI8(av0, wO8[0], z4);                                                      \
    i32x4 aI1 = MFI8(av1, wI8[1], z4);                                                      \
    i32x4 aF1 = MFI8(av1, wF8[1], z4);                                                      \
    i32x4 aG1 = MFI8(av1, wG8[1], z4);                                                      \
    i32x4 aO1 = MFI8(av1, wO8[1], z4);                                                      \
    if (q < 3){                                                                             \
        float bI = fmaf(gp.y, wgy4[0], fmaf(gp.x, wgx4[0], (float)xv[0]));                  \
        float bF = fmaf(gp.y, wgy4[1], fmaf(gp.x, wgx4[1], (float)xv[1]));                  \
        float bG = fmaf(gp.y, wgy4[2], fmaf(gp.x, wgx4[2], (float)xv[2]));                  \
        float bO = fmaf(gp.y, wgy4[3], fmaf(gp.x, wgx4[3], (float)xv[3]));                  \
        float yI = fmaf((float)(aI0[0] + aI1[0]), dq4[0], bI);                              \
        float yF = fmaf((float)(aF0[0] + aF1[0]), dq4[1], bF);                              \
        float yG = fmaf((float)(aG0[0] + aG1[0]), dq4[2], bG);                              \
        float yO = fmaf((float)(aO0[0] + aO1[0]), dq4[3], bO);                              \
        if ((T) < len_q){                                                                   \
            float si = rcp_f(1.f + exp2_f(yI));                                             \
            float sf = rcp_f(1.f + exp2_f(yF));                                             \
            float so = rcp_f(1.f + exp2_f(yO));                                             \
            float tg = fmaf(-2.f, rcp_f(1.f + exp2_f(yG)), 1.f);                            \
            creg = fmaf(sf, creg, si * tg);                                                 \
            float th = fmaf(-2.f, rcp_f(1.f + exp2_f(S_TANH * creg)), 1.f);                 \
            hreg = so * th;                                                                 \
        }                                                                                   \
        int hi8 = (int)rintf(hreg * 127.f);                                                 \
        A_s[P1][q][u] = (signed char)hi8;                                                   \
        if ((T) < len_q){                                                                   \
            while ((T) == next_t){                                                          \
                stash[(size_t)ev_sl_s[qc][evp]*HH + u] = hreg;                              \
                ++evp;                                                                      \
                next_t = (evp < nev_q) ? ev_t_s[qc][evp] : (1<<30);                         \
            }                                                                               \
        }                                                                                   \
    }                                                                                       \
    if (((K) & 7) == 7) asm volatile("s_waitcnt vmcnt(0)" ::: "memory");                    \
    asm volatile("s_waitcnt lgkmcnt(0)" ::: "memory");                                      \
    __builtin_amdgcn_s_barrier();                                                           \
    asm volatile("" ::: "memory");                                                          \
}

    for (int t = 0; t < maxlen; t += 16){
        STEP(t+0,  0,1, 0)  STEP(t+1,  1,0, 1)  STEP(t+2,  0,1, 2)  STEP(t+3,  1,0, 3)
        STEP(t+4,  0,1, 4)  STEP(t+5,  1,0, 5)  STEP(t+6,  0,1, 6)  STEP(t+7,  1,0, 7)
        STEP(t+8,  0,1, 8)  STEP(t+9,  1,0, 9)  STEP(t+10, 0,1,10)  STEP(t+11, 1,0,11)
        STEP(t+12, 0,1,12)  STEP(t+13, 1,0,13)  STEP(t+14, 0,1,14)  STEP(t+15, 1,0,15)
    }
#undef STEP
}

// ---------------- fsim via MFMA: 64 rows/block, 3 GEMMs [64x128]@[128x128] + nonlin, in-place ----------------
#define FROWA 144
#define FROWF 132
__launch_bounds__(256)
__global__ void fsim_kernel(float* __restrict__ stash, const f16* __restrict__ Wfs,
                            const float* __restrict__ bi, const float* __restrict__ bc, const float* __restrict__ bo,
                            const int* __restrict__ sub_ta, const int* __restrict__ sub_tf,
                            const int* __restrict__ sub_a, const int* __restrict__ sub_f,
                            const int* __restrict__ len_t, const int* __restrict__ len_a, const int* __restrict__ len_f)
{
    __shared__ f16   hA[64][FROWA];
    __shared__ float hF[64][FROWF];
    __shared__ float bia[3][128];

    const int tid  = threadIdx.x;
    const int lane = tid & 63;
    const int wv   = tid >> 6;
    const int q    = lane >> 4;
    const int li   = lane & 15;
    const int base = blockIdx.x * 64;

    {
        const int row = tid >> 2, cg = tid & 3;
        const int grow = base + row;
        bool valid = true;
        if (grow < 10240){
            int g = grow / 2560, rr = grow % 2560, b = rr / 10;
            int sub, len;
            if (g == 0){ sub = sub_ta[rr]; len = len_t[b]; }
            else if (g == 1){ sub = sub_tf[rr]; len = len_t[b]; }
            else if (g == 2){ sub = sub_a[rr]; len = len_a[b]; }
            else { sub = sub_f[rr]; len = len_f[b]; }
            valid = (sub - 1) < len;
        }
        const f32x4* src = (const f32x4*)(stash + (size_t)grow*HH + cg*32);
        #pragma unroll
        for (int j2 = 0; j2 < 4; ++j2){
            f32x4 z = {0.f,0.f,0.f,0.f};
            f32x4 a = valid ? src[j2*2]     : z;
            f32x4 b = valid ? src[j2*2 + 1] : z;
            f16x8 t;
            t[0]=(f16)a[0]; t[1]=(f16)a[1]; t[2]=(f16)a[2]; t[3]=(f16)a[3];
            t[4]=(f16)b[0]; t[5]=(f16)b[1]; t[6]=(f16)b[2]; t[7]=(f16)b[3];
            *reinterpret_cast<f16x8*>(&hA[row][cg*32 + j2*8]) = t;
            *reinterpret_cast<f32x4*>(&hF[row][cg*32 + j2*8])     = a;
            *reinterpret_cast<f32x4*>(&hF[row][cg*32 + j2*8 + 4]) = b;
        }
    }
    if (tid < 384){
        int w = tid >> 7, uu = tid & 127;
        bia[w][uu] = ((w==0) ? bi : (w==1) ? bc : bo)[uu];
    }
    __syncthreads();

    f16x8 av[4];
    {
        const f16* Arow = &hA[wv*16 + li][q << 3];
        #pragma unroll
        for (int ks = 0; ks < 4; ++ks)
            av[ks] = *reinterpret_cast<const f16x8*>(Arow + ks*32);
    }

    #pragma unroll
    for (int ct = 0; ct < 8; ++ct){
        const int col = ct*16 + li;
        f32x4 aI = {0.f,0.f,0.f,0.f}, aC = aI, aO = aI;
        #pragma unroll
        for (int ks = 0; ks < 4; ++ks){
            f16x8 bI8 = *reinterpret_cast<const f16x8*>(Wfs +           (size_t)col*128 + ks*32 + (q<<3));
            f16x8 bC8 = *reinterpret_cast<const f16x8*>(Wfs + 16384 +   (size_t)col*128 + ks*32 + (q<<3));
            f16x8 bO8 = *reinterpret_cast<const f16x8*>(Wfs + 32768 +   (size_t)col*128 + ks*32 + (q<<3));
            aI = MF(av[ks], bI8, aI);
            aC = MF(av[ks], bC8, aC);
            aO = MF(av[ks], bO8, aO);
        }
        const float BI = bia[0][col], BC = bia[1][col], BO = bia[2][col];
        #pragma unroll
        for (int reg = 0; reg < 4; ++reg){
            const int lrow = wv*16 + q*4 + reg;
            float C   = sigm_e(aI[reg] + BI) * tanh_e(aC[reg] + BC);
            float out = sigm_e(aO[reg] + BO) * tanh_e(C) + hF[lrow][col];
            stash[(size_t)(base + lrow)*HH + col] = out;
        }
    }
}

// ---------------- distances: out = exp(-||u - v||) ----------------
__global__ void dist_kernel(const float* __restrict__ fs, float* __restrict__ out)
{
    int gid = blockIdx.x * 256 + threadIdx.x;
    int pair = gid >> 6, ln = gid & 63;
    if (pair >= 5632) return;
    int ia, ib;
    if (pair < 256){ ia = 10240 + pair; ib = 10240 + 256 + pair; }
    else if (pair < 512){ int j = pair - 256; ia = 10240 + j; ib = 10240 + 512 + j; }
    else if (pair < 3072){ int j = pair - 512; ia = j; ib = 5120 + j; }
    else { int j = pair - 3072; ia = 2560 + j; ib = 7680 + j; }
    float d = 0.f;
    #pragma unroll
    for (int k = 0; k < 2; ++k){
        int kk = ln + k*64;
        float df = fs[(size_t)ia*HH + kk] - fs[(size_t)ib*HH + kk];
        d = fmaf(df, df, d);
    }
    #pragma unroll
    for (int off = 32; off > 0; off >>= 1) d += __shfl_xor(d, off);
    if (ln == 0) out[pair] = __expf(-sqrtf(d));
}

extern "C" void kernel_launch(void* const* d_in, const int* in_sizes, int n_in,
                              void* d_out, int out_size, void* d_ws, size_t ws_size,
                              hipStream_t stream)
{
    (void)n_in; (void)out_size; (void)ws_size;
    const float* traj_gps = (const float*)d_in[0];
    const int*   traj_grid = (const int*)d_in[2];
    const int*   traj_len = (const int*)d_in[4];
    const int*   sub_ta = (const int*)d_in[5];
    const int*   sub_tf = (const int*)d_in[6];
    const float* anc_gps = (const float*)d_in[7];
    const int*   anc_grid = (const int*)d_in[9];
    const int*   anc_len = (const int*)d_in[11];
    const int*   sub_a = (const int*)d_in[12];
    const float* far_gps = (const float*)d_in[13];
    const int*   far_grid = (const int*)d_in[15];
    const int*   far_len = (const int*)d_in[17];
    const int*   sub_f = (const int*)d_in[18];
    const float* E    = (const float*)d_in[19];
    const float* W_ih = (const float*)d_in[20];
    const float* W_hh = (const float*)d_in[21];
    const float* b_ih = (const float*)d_in[22];
    const float* b_hh = (const float*)d_in[23];
    const float* Wi = (const float*)d_in[24];
    const float* bi = (const float*)d_in[25];
    const float* Wc = (const float*)d_in[26];
    const float* bc = (const float*)d_in[27];
    const float* Wo = (const float*)d_in[28];
    const float* bo = (const float*)d_in[29];

    const int NW_rt = in_sizes[19] / HH;   // 50000

    char* p = (char*)d_ws;
    signed char* Whh_q = (signed char*)p; p += (size_t)512*128;
    float* dq_o   = (float*)p; p += 512*4;
    f16* Wih_p    = (f16*)p;   p += (size_t)512*128*2;
    float* Wg_o   = (float*)p; p += 1024*4;
    float* bsum_o = (float*)p; p += 512*4;
    f16* Wfs      = (f16*)p;   p += (size_t)3*128*128*2;
    int* order    = (int*)p;   p += 768*4;
    int* slen     = (int*)p;   p += 768*4;
    int* ev_t     = (int*)p;   p += 768*NEV*4;
    int* ev_slot  = (int*)p;   p += 768*NEV*4;
    int* nev      = (int*)p;   p += 768*4;
    float* stash  = (float*)p; p += (size_t)11008*128*4;
    f16* xgT      = (f16*)p;   p += (size_t)NW_rt*512*2;

    pack_kernel<<<576, 256, 0, stream>>>(W_ih, W_hh, b_ih, b_hh, Wi, Wc, Wo,
                                         Whh_q, dq_o, Wih_p, Wg_o, bsum_o, Wfs);
    xg_gemm<<<(NW_rt + 127)/128, 512, 0, stream>>>(E, Wih_p, bsum_o, xgT, NW_rt);
    sched_kernel<<<1, 768, 0, stream>>>(traj_len, anc_len, far_len, sub_ta, sub_tf, sub_a, sub_f,
                                        order, slen, ev_t, ev_slot, nev);
    lstm_kernel<<<256, 512, 0, stream>>>(traj_gps, anc_gps, far_gps, traj_grid, anc_grid, far_grid,
                                         xgT, Whh_q, dq_o, Wg_o, order, slen, ev_t, ev_slot, nev, stash);
    fsim_kernel<<<172, 256, 0, stream>>>(stash, Wfs, bi, bc, bo, sub_ta, sub_tf, sub_a, sub_f,
                                         traj_len, anc_len, far_len);
    dist_kernel<<<1408, 256, 0, stream>>>(stash, (float*)d_out);
}